// Round 12
// baseline (183.137 us; speedup 1.0000x reference)
//
#include <hip/hip_runtime.h>
#include <hip/hip_bf16.h>

// dims
#define NB2 128
#define LQK 256
#define DIM 256
#define NH 8
#define CC 32

typedef __bf16 bf16x8 __attribute__((ext_vector_type(8)));
typedef __bf16 bf16x4 __attribute__((ext_vector_type(4)));
typedef float f32x4 __attribute__((ext_vector_type(4)));

#define MFMA16 __builtin_amdgcn_mfma_f32_16x16x32_bf16

// LDS tile row stride (bf16): 64 k + 8 pad
#define TP 72

#define NTOK ((size_t)NB2 * LQK * NH * CC)   // 8,388,608

// async global->LDS, 16B per lane; LDS dest is wave-uniform base + lane*16
static __device__ __forceinline__ void gload_lds16(const void* g, void* l) {
    __builtin_amdgcn_global_load_lds(
        (const __attribute__((address_space(1))) unsigned int*)g,
        (__attribute__((address_space(3))) unsigned int*)l,
        16, 0, 0);
}

#define WAITV(N) do { asm volatile("s_waitcnt vmcnt(" #N ")" ::: "memory"); \
                      __builtin_amdgcn_sched_barrier(0); } while (0)

// ---------------- Kernel 0a: weights fp32 -> bf16 -------------------------
__global__ __launch_bounds__(256) void k_wcvt(
    const float* __restrict__ Wq, const float* __restrict__ Wk,
    const float* __restrict__ Wv, const float* __restrict__ Wg,
    const float* __restrict__ Wo, __bf16* __restrict__ dst)
{
    int i = (blockIdx.x * 256 + threadIdx.x) * 4;
    int mat = i >> 16;
    int off = i & 65535;
    const float* src = (mat == 0) ? Wq : (mat == 1) ? Wk : (mat == 2) ? Wv
                      : (mat == 3) ? Wg : Wo;
    f32x4 v = *(const f32x4*)(src + off);
    __bf16* d = dst + ((size_t)mat << 16) + off;
    d[0] = (__bf16)v[0]; d[1] = (__bf16)v[1]; d[2] = (__bf16)v[2]; d[3] = (__bf16)v[3];
}

// ---------------- Kernel 0b: activations fp32 -> bf16 ---------------------
__global__ __launch_bounds__(256) void k_acvt(
    const float* __restrict__ qd, const float* __restrict__ kvd,
    __bf16* __restrict__ qbf, __bf16* __restrict__ kvbf)
{
    size_t i = ((size_t)blockIdx.x * 256 + threadIdx.x) * 8;
    const float* src;
    __bf16* dst;
    if (i < NTOK) { src = qd + i; dst = qbf + i; }
    else          { src = kvd + (i - NTOK); dst = kvbf + (i - NTOK); }
    f32x4 a = *(const f32x4*)src;
    f32x4 b = *(const f32x4*)(src + 4);
    bf16x8 r;
    r[0] = (__bf16)a[0]; r[1] = (__bf16)a[1]; r[2] = (__bf16)a[2]; r[3] = (__bf16)a[3];
    r[4] = (__bf16)b[0]; r[5] = (__bf16)b[1]; r[6] = (__bf16)b[2]; r[7] = (__bf16)b[3];
    *(bf16x8*)dst = r;
}

// ---------------- Kernel 1: QKVG projection (tiled GEMM, bf16 A) ----------
__global__ __launch_bounds__(256, 2) void k_proj(
    const __bf16* __restrict__ qbf, const __bf16* __restrict__ kvbf,
    const __bf16* __restrict__ wBF, const float* __restrict__ bg,
    __bf16* __restrict__ wsq, __bf16* __restrict__ wsk,
    __bf16* __restrict__ wsvT, __bf16* __restrict__ wsgT)
{
    __shared__ __bf16 At[2][128][TP];
    __shared__ __bf16 Bt[2][128][TP];

    const int mb = blockIdx.x, nb = blockIdx.y;
    const int t = nb >> 1;                       // 0=q 1=k 2=v 3=g
    const __bf16* X = (t == 0 || t == 3) ? qbf : kvbf;
    const __bf16* W = wBF + ((size_t)t << 16) + (size_t)((nb & 1) * 128) * 256;

    const int tid = threadIdx.x;
    const int lane = tid & 63, w = tid >> 6;
    const int g = lane >> 4, kg = g * 8, c0 = lane & 15;
    const int mq = (w >> 1) * 64, nq = (w & 1) * 64;
    const int m0 = mb * 128;
    const int srow = tid >> 1, shalf = (tid & 1) * 32;

    f32x4 acc[4][4] = {};
    bf16x8 av[4], bv[4];
    auto load_stage = [&](int kit) {
        const __bf16* ap = X + (size_t)(m0 + srow) * DIM + kit * 64 + shalf;
        const __bf16* bp = W + (size_t)srow * 256 + kit * 64 + shalf;
#pragma unroll
        for (int j = 0; j < 4; j++) {
            av[j] = *(const bf16x8*)(ap + j * 8);
            bv[j] = *(const bf16x8*)(bp + j * 8);
        }
    };
    auto write_stage = [&](int buf) {
#pragma unroll
        for (int j = 0; j < 4; j++) {
            *(bf16x8*)(&At[buf][srow][shalf + j * 8]) = av[j];
            *(bf16x8*)(&Bt[buf][srow][shalf + j * 8]) = bv[j];
        }
    };

    load_stage(0);
    write_stage(0);
    __syncthreads();

#pragma unroll
    for (int kit = 0; kit < 4; kit++) {
        if (kit < 3) load_stage(kit + 1);
        const int cur = kit & 1;
#pragma unroll
        for (int ks = 0; ks < 2; ks++) {
            bf16x8 af[4], bf_[4];
#pragma unroll
            for (int mi = 0; mi < 4; mi++)
                af[mi] = *(const bf16x8*)(&At[cur][mq + mi * 16 + c0][ks * 32 + kg]);
#pragma unroll
            for (int ni = 0; ni < 4; ni++)
                bf_[ni] = *(const bf16x8*)(&Bt[cur][nq + ni * 16 + c0][ks * 32 + kg]);
#pragma unroll
            for (int mi = 0; mi < 4; mi++)
#pragma unroll
                for (int ni = 0; ni < 4; ni++)
                    acc[mi][ni] = MFMA16(af[mi], bf_[ni], acc[mi][ni], 0, 0, 0);
        }
        if (kit < 3) write_stage(cur ^ 1);
        __syncthreads();
    }

    // ---- epilogue ----
#pragma unroll
    for (int ni = 0; ni < 4; ni++) {
        const int nloc = (nb & 1) * 128 + nq + ni * 16 + c0;
        const int h = nloc >> 5, c = nloc & 31;
        const float bg_ = (t == 3) ? bg[nloc] : 0.0f;
#pragma unroll
        for (int mi = 0; mi < 4; mi++) {
            const int mbase = m0 + mq + mi * 16 + g * 4;
            const int b2 = mbase >> 8;
            if (t == 2) {
                bf16x4 pk;
#pragma unroll
                for (int reg = 0; reg < 4; reg++) pk[reg] = (__bf16)acc[mi][ni][reg];
                *(bf16x4*)(&wsvT[((size_t)(b2 * NH + h) * CC + c) * LQK + (mbase & 255)]) = pk;
            } else if (t == 3) {
                bf16x4 pk;
#pragma unroll
                for (int reg = 0; reg < 4; reg++)
                    pk[reg] = (__bf16)(1.0f / (1.0f + __expf(-(acc[mi][ni][reg] + bg_))));
                *(bf16x4*)(&wsgT[((size_t)(b2 * NH + h) * CC + c) * LQK + (mbase & 255)]) = pk;
            } else {
#pragma unroll
                for (int reg = 0; reg < 4; reg++) {
                    const int l = (mbase + reg) & 255;
                    float v = acc[mi][ni][reg];
                    size_t idx = ((size_t)(b2 * NH + h) * LQK + l) * CC + c;
                    if (t == 0) wsq[idx] = (__bf16)(v * 0.17677669529663689f);
                    else        wsk[idx] = (__bf16)v;
                }
            }
        }
    }
}

// ---------------- Kernel 2: attention (barrier-free, wave-private) --------
// grid 4096; XCD head-grouping. Each wave owns 16 q-rows, stages its own
// bias strip (4 KB/chunk, dbuf) via gload_lds, prefetches K/V/nbb to regs
// one chunk ahead, and paces itself with per-wave counted vmcnt. No
// __syncthreads anywhere.
__global__ __launch_bounds__(256, 3) void k_attn(
    const __bf16* __restrict__ wsq, const __bf16* __restrict__ wsk,
    const __bf16* __restrict__ wsvT, const __bf16* __restrict__ wsgT,
    const float* __restrict__ bias, const float* __restrict__ nbb,
    __bf16* __restrict__ wswa)
{
    __shared__ float  Bw[4][2][16][64];   // per-wave bias strips, dbuf: 32 KB
    __shared__ __bf16 P[4][16][66];       // per-wave P, padded: 8.25 KB

    const int tid = threadIdx.x;
    // ---- XCD head-grouping swizzle ----
    const int u0 = blockIdx.x;
    const int xcd = u0 & 7, slot = u0 >> 3;
    const int head = xcd + 8 * (slot >> 2);
    const int qt = slot & 3;
    const int b2 = head >> 3, h = head & 7;

    const int lane = tid & 63, w = tid >> 6;
    const int g = lane >> 4, kg = g * 8, c0 = lane & 15;
    const int qbase = qt * 64 + w * 16;
    const int q = qbase + c0;

    const __bf16* qp = wsq + (size_t)(b2 * NH + h) * LQK * CC;
    const __bf16* kp = wsk + (size_t)(b2 * NH + h) * LQK * CC;
    const __bf16* vT = wsvT + (size_t)(b2 * NH + h) * CC * LQK;
    const __bf16* gT = wsgT + (size_t)(b2 * NH + h) * CC * LQK;
    const float* np = nbb + ((size_t)h * LQK + q) * LQK;
    const float* bpw = bias + ((size_t)(b2 * NH + h) * LQK + qbase) * LQK; // wave's 16 rows

    // stage bias chunk c into this wave's strip buf: exactly 4 gload_lds
    // write: phys slot jj holds source unit jj^row (row 0..15 in strip)
    auto stageB = [&](int buf, int c) {
        const int rsub = lane >> 4, jj = lane & 15;
#pragma unroll
        for (int i = 0; i < 4; i++) {
            const int row = i * 4 + rsub;           // 0..15
            const int uu = jj ^ row;                // src-unit swizzle
            gload_lds16(bpw + (size_t)row * LQK + c * 64 + uu * 4,
                        &Bw[w][buf][i * 4][0]);
        }
    };

    bf16x8 qf = *(const bf16x8*)(qp + (size_t)q * CC + kg);

    bf16x8 kfb[2][4], vfb[2][4];
    f32x4 nbr[2][4];
    // 12 reg loads: K(4) + V(4) + nbb(4) for chunk c
    auto loadKVN = [&](int buf, int c) {
#pragma unroll
        for (int j = 0; j < 4; j++)
            kfb[buf][j] = *(const bf16x8*)(kp + (size_t)(c * 64 + j * 16 + c0) * CC + kg);
#pragma unroll
        for (int h2 = 0; h2 < 2; h2++)
#pragma unroll
            for (int vn = 0; vn < 2; vn++)
                vfb[buf][h2 * 2 + vn] = *(const bf16x8*)(
                    vT + (size_t)(vn * 16 + c0) * LQK + c * 64 + h2 * 32 + kg);
#pragma unroll
        for (int j = 0; j < 4; j++)
            nbr[buf][j] = *(const f32x4*)(np + c * 64 + j * 16 + g * 4);
    };

    // ---- prologue: S0, KVN0, S1 -> wait S0+KVN0 (S1 floats) ----
    stageB(0, 0);
    loadKVN(0, 0);
    stageB(1, 1);
    WAITV(4);

    float l = 0.0f;
    f32x4 o[2] = {};

#pragma unroll
    for (int c = 0; c < 4; c++) {
        const int cur = c & 1;
        if (c < 3) loadKVN(cur ^ 1, c + 1);       // 12 loads, consumed next chunk

        // ---- QK^T + exp from strip/regs (S_c, KVN_c both drained) ----
        float csum = 0.0f;
#pragma unroll
        for (int j = 0; j < 4; j++) {
            const int phys = (j * 4 + g) ^ c0;    // read swizzle
            f32x4 b4 = *(const f32x4*)(&Bw[w][cur][c0][phys * 4]);
            f32x4 cc;
#pragma unroll
            for (int r2 = 0; r2 < 4; r2++) cc[r2] = b4[r2] + nbr[cur][j][r2];
            f32x4 s = MFMA16(kfb[cur][j], qf, cc, 0, 0, 0);
            bf16x4 pk;
#pragma unroll
            for (int r2 = 0; r2 < 4; r2++) {
                float e = __expf(s[r2]);          // no max-sub: |s| bounded ~20
                csum += e;
                pk[r2] = (__bf16)e;
            }
            *(bf16x4*)(&P[w][c0][j * 16 + g * 4]) = pk;
        }
        l += csum;

        // buf cur's bias reads done -> safe to overwrite with chunk c+2
        if (c < 2) stageB(cur, c + 2);

        // ---- PV from regs + wave-private P ----
#pragma unroll
        for (int h2 = 0; h2 < 2; h2++) {
            bf16x8 pa = *(const bf16x8*)(&P[w][c0][h2 * 32 + kg]);
#pragma unroll
            for (int vn = 0; vn < 2; vn++)
                o[vn] = MFMA16(pa, vfb[cur][h2 * 2 + vn], o[vn], 0, 0, 0);
        }

        // drain KVN_{c+1} + S_{c+1}; leave S_{c+2} (newest 4) in flight
        if (c < 2)      WAITV(4);
        else if (c == 2) WAITV(0);
    }

    l += __shfl_xor(l, 16);
    l += __shfl_xor(l, 32);
    const float inv = 1.0f / l;

    // ---- 1/sum, gate (transposed, bf16x4), store ----
#pragma unroll
    for (int vn = 0; vn < 2; vn++) {
        const int c = vn * 16 + c0;
        bf16x4 g4 = *(const bf16x4*)(gT + (size_t)c * LQK + qbase + g * 4);
#pragma unroll
        for (int reg = 0; reg < 4; reg++) {
            const int row = qbase + g * 4 + reg;
            const float invr = __shfl(inv, g * 4 + reg, 64);
            const float val = o[vn][reg] * invr * (float)g4[reg];
            wswa[((size_t)(b2 * LQK + row)) * (NH * CC) + h * CC + c] = (__bf16)val;
        }
    }
}

// ---------------- Kernel 3: output projection (tiled GEMM) ----------------
__global__ __launch_bounds__(256, 2) void k_out(
    const __bf16* __restrict__ wa, const __bf16* __restrict__ wBF,
    const float* __restrict__ bo, float* __restrict__ out)
{
    __shared__ __bf16 At[2][128][TP];
    __shared__ __bf16 Bt[2][128][TP];

    const int mb = blockIdx.x, nb = blockIdx.y;
    const __bf16* W = wBF + ((size_t)4 << 16) + (size_t)(nb * 128) * 256;

    const int tid = threadIdx.x;
    const int lane = tid & 63, w = tid >> 6;
    const int g = lane >> 4, kg = g * 8, c0 = lane & 15;
    const int mq = (w >> 1) * 64, nq = (w & 1) * 64;
    const int m0 = mb * 128;
    const int srow = tid >> 1, shalf = (tid & 1) * 32;

    f32x4 acc[4][4] = {};
    bf16x8 av[4], bv[4];
    auto load_stage = [&](int kit) {
        const __bf16* ap = wa + (size_t)(m0 + srow) * 256 + kit * 64 + shalf;
        const __bf16* bp = W + (size_t)srow * 256 + kit * 64 + shalf;
#pragma unroll
        for (int j = 0; j < 4; j++) {
            av[j] = *(const bf16x8*)(ap + j * 8);
            bv[j] = *(const bf16x8*)(bp + j * 8);
        }
    };
    auto write_stage = [&](int buf) {
#pragma unroll
        for (int j = 0; j < 4; j++) {
            *(bf16x8*)(&At[buf][srow][shalf + j * 8]) = av[j];
            *(bf16x8*)(&Bt[buf][srow][shalf + j * 8]) = bv[j];
        }
    };

    load_stage(0);
    write_stage(0);
    __syncthreads();

#pragma unroll
    for (int kit = 0; kit < 4; kit++) {
        if (kit < 3) load_stage(kit + 1);
        const int cur = kit & 1;
#pragma unroll
        for (int ks = 0; ks < 2; ks++) {
            bf16x8 af[4], bf_[4];
#pragma unroll
            for (int mi = 0; mi < 4; mi++)
                af[mi] = *(const bf16x8*)(&At[cur][mq + mi * 16 + c0][ks * 32 + kg]);
#pragma unroll
            for (int ni = 0; ni < 4; ni++)
                bf_[ni] = *(const bf16x8*)(&Bt[cur][nq + ni * 16 + c0][ks * 32 + kg]);
#pragma unroll
            for (int mi = 0; mi < 4; mi++)
#pragma unroll
                for (int ni = 0; ni < 4; ni++)
                    acc[mi][ni] = MFMA16(af[mi], bf_[ni], acc[mi][ni], 0, 0, 0);
        }
        if (kit < 3) write_stage(cur ^ 1);
        __syncthreads();
    }

#pragma unroll
    for (int ni = 0; ni < 4; ni++) {
        const int n = nb * 128 + nq + ni * 16 + c0;
        const float bo_ = bo[n];
#pragma unroll
        for (int mi = 0; mi < 4; mi++) {
            const int mbase = m0 + mq + mi * 16 + g * 4;
#pragma unroll
            for (int reg = 0; reg < 4; reg++)
                out[(size_t)(mbase + reg) * 256 + n] = acc[mi][ni][reg] + bo_;
        }
    }
}

// ---------------- launcher ------------------------------------------------
extern "C" void kernel_launch(void* const* d_in, const int* in_sizes, int n_in,
                              void* d_out, int out_size, void* d_ws, size_t ws_size,
                              hipStream_t stream) {
    const float* qd  = (const float*)d_in[0];
    const float* kvd = (const float*)d_in[1];
    const float* bias = (const float*)d_in[2];
    const float* nbb = (const float*)d_in[3];
    const float* Wq = (const float*)d_in[4];
    const float* Wk = (const float*)d_in[5];
    const float* Wv = (const float*)d_in[6];
    const float* Wg = (const float*)d_in[7];
    const float* bg = (const float*)d_in[8];
    const float* Wo = (const float*)d_in[9];
    const float* bo = (const float*)d_in[10];
    float* out = (float*)d_out;

    __bf16* ws = (__bf16*)d_ws;
    __bf16* wsq  = ws;
    __bf16* wsk  = wsq + NTOK;
    __bf16* wsvT = wsk + NTOK;
    __bf16* wsgT = wsvT + NTOK;
    __bf16* wBF  = wsgT + NTOK;            // 5 * 65536 bf16 weights
    __bf16* qbf  = wBF + 5 * 65536;        // activations bf16 (dead after k_proj)
    __bf16* kvbf = qbf + NTOK;
    __bf16* wswa = qbf;                    // alias: written by k_attn after k_proj

    k_wcvt<<<dim3(320), 256, 0, stream>>>(Wq, Wk, Wv, Wg, Wo, wBF);
    k_acvt<<<dim3(8192), 256, 0, stream>>>(qd, kvd, qbf, kvbf);
    k_proj<<<dim3(256, 8), 256, 0, stream>>>(qbf, kvbf, wBF, bg,
                                             wsq, wsk, wsvT, wsgT);
    k_attn<<<dim3(4096), 256, 0, stream>>>(wsq, wsk, wsvT, wsgT, bias, nbb, wswa);
    k_out<<<dim3(256, 2), 256, 0, stream>>>(wswa, wBF, bo, out);
}

// Round 14
// 168.469 us; speedup vs baseline: 1.0871x; 1.0871x over previous
//
#include <hip/hip_runtime.h>
#include <hip/hip_bf16.h>

// dims
#define NB2 128
#define LQK 256
#define DIM 256
#define NH 8
#define CC 32

typedef __bf16 bf16x8 __attribute__((ext_vector_type(8)));
typedef __bf16 bf16x4 __attribute__((ext_vector_type(4)));
typedef float f32x4 __attribute__((ext_vector_type(4)));

#define MFMA16 __builtin_amdgcn_mfma_f32_16x16x32_bf16

// LDS tile row stride (bf16): 64 k + 8 pad.  NOTE: must stay ≡0 mod 8
// elements (16 B) — b128 LDS reads require 16-B alignment (round-13 NaN).
#define TP 72

#define NTOK ((size_t)NB2 * LQK * NH * CC)   // 8,388,608

// async global->LDS, 16B per lane; LDS dest is wave-uniform base + lane*16
static __device__ __forceinline__ void gload_lds16(const void* g, void* l) {
    __builtin_amdgcn_global_load_lds(
        (const __attribute__((address_space(1))) unsigned int*)g,
        (__attribute__((address_space(3))) unsigned int*)l,
        16, 0, 0);
}

// ---------------- Kernel 0: fp32 -> bf16 (activations + weights) ----------
// blocks 0..8191: qd/kvd (8 elems/thread). blocks 8192..8511: 5 weights.
__global__ __launch_bounds__(256) void k_cvt(
    const float* __restrict__ qd, const float* __restrict__ kvd,
    const float* __restrict__ Wq, const float* __restrict__ Wk,
    const float* __restrict__ Wv, const float* __restrict__ Wg,
    const float* __restrict__ Wo,
    __bf16* __restrict__ qbf, __bf16* __restrict__ kvbf,
    __bf16* __restrict__ wBF)
{
    const int b = blockIdx.x;
    if (b < 8192) {
        size_t i = ((size_t)b * 256 + threadIdx.x) * 8;
        const float* src;
        __bf16* dst;
        if (i < NTOK) { src = qd + i; dst = qbf + i; }
        else          { src = kvd + (i - NTOK); dst = kvbf + (i - NTOK); }
        f32x4 a = *(const f32x4*)src;
        f32x4 c = *(const f32x4*)(src + 4);
        bf16x8 r;
        r[0] = (__bf16)a[0]; r[1] = (__bf16)a[1]; r[2] = (__bf16)a[2]; r[3] = (__bf16)a[3];
        r[4] = (__bf16)c[0]; r[5] = (__bf16)c[1]; r[6] = (__bf16)c[2]; r[7] = (__bf16)c[3];
        *(bf16x8*)dst = r;
    } else {
        int i = ((b - 8192) * 256 + threadIdx.x) * 4;
        int mat = i >> 16;
        int off = i & 65535;
        const float* src = (mat == 0) ? Wq : (mat == 1) ? Wk : (mat == 2) ? Wv
                          : (mat == 3) ? Wg : Wo;
        f32x4 v = *(const f32x4*)(src + off);
        __bf16* d = wBF + ((size_t)mat << 16) + off;
        d[0] = (__bf16)v[0]; d[1] = (__bf16)v[1]; d[2] = (__bf16)v[2]; d[3] = (__bf16)v[3];
    }
}

// ---------------- Kernel 1: QKVG projection (tiled GEMM, bf16 A) ----------
__global__ __launch_bounds__(256, 2) void k_proj(
    const __bf16* __restrict__ qbf, const __bf16* __restrict__ kvbf,
    const __bf16* __restrict__ wBF, const float* __restrict__ bg,
    __bf16* __restrict__ wsq, __bf16* __restrict__ wsk,
    __bf16* __restrict__ wsvT, __bf16* __restrict__ wsgT)
{
    __shared__ __bf16 At[2][128][TP];
    __shared__ __bf16 Bt[2][128][TP];

    const int mb = blockIdx.x, nb = blockIdx.y;
    const int t = nb >> 1;                       // 0=q 1=k 2=v 3=g
    const __bf16* X = (t == 0 || t == 3) ? qbf : kvbf;
    const __bf16* W = wBF + ((size_t)t << 16) + (size_t)((nb & 1) * 128) * 256;

    const int tid = threadIdx.x;
    const int lane = tid & 63, w = tid >> 6;
    const int g = lane >> 4, kg = g * 8, c0 = lane & 15;
    const int mq = (w >> 1) * 64, nq = (w & 1) * 64;
    const int m0 = mb * 128;
    const int srow = tid >> 1, shalf = (tid & 1) * 32;

    f32x4 acc[4][4] = {};
    bf16x8 av[4], bv[4];
    auto load_stage = [&](int kit) {
        const __bf16* ap = X + (size_t)(m0 + srow) * DIM + kit * 64 + shalf;
        const __bf16* bp = W + (size_t)srow * 256 + kit * 64 + shalf;
#pragma unroll
        for (int j = 0; j < 4; j++) {
            av[j] = *(const bf16x8*)(ap + j * 8);
            bv[j] = *(const bf16x8*)(bp + j * 8);
        }
    };
    auto write_stage = [&](int buf) {
#pragma unroll
        for (int j = 0; j < 4; j++) {
            *(bf16x8*)(&At[buf][srow][shalf + j * 8]) = av[j];
            *(bf16x8*)(&Bt[buf][srow][shalf + j * 8]) = bv[j];
        }
    };

    load_stage(0);
    write_stage(0);
    __syncthreads();

#pragma unroll
    for (int kit = 0; kit < 4; kit++) {
        if (kit < 3) load_stage(kit + 1);
        const int cur = kit & 1;
#pragma unroll
        for (int ks = 0; ks < 2; ks++) {
            bf16x8 af[4], bf_[4];
#pragma unroll
            for (int mi = 0; mi < 4; mi++)
                af[mi] = *(const bf16x8*)(&At[cur][mq + mi * 16 + c0][ks * 32 + kg]);
#pragma unroll
            for (int ni = 0; ni < 4; ni++)
                bf_[ni] = *(const bf16x8*)(&Bt[cur][nq + ni * 16 + c0][ks * 32 + kg]);
#pragma unroll
            for (int mi = 0; mi < 4; mi++)
#pragma unroll
                for (int ni = 0; ni < 4; ni++)
                    acc[mi][ni] = MFMA16(af[mi], bf_[ni], acc[mi][ni], 0, 0, 0);
        }
        if (kit < 3) write_stage(cur ^ 1);
        __syncthreads();
    }

    // ---- epilogue ----
#pragma unroll
    for (int ni = 0; ni < 4; ni++) {
        const int nloc = (nb & 1) * 128 + nq + ni * 16 + c0;
        const int h = nloc >> 5, c = nloc & 31;
        const float bg_ = (t == 3) ? bg[nloc] : 0.0f;
#pragma unroll
        for (int mi = 0; mi < 4; mi++) {
            const int mbase = m0 + mq + mi * 16 + g * 4;
            const int b2 = mbase >> 8;
            if (t == 2) {
                bf16x4 pk;
#pragma unroll
                for (int reg = 0; reg < 4; reg++) pk[reg] = (__bf16)acc[mi][ni][reg];
                *(bf16x4*)(&wsvT[((size_t)(b2 * NH + h) * CC + c) * LQK + (mbase & 255)]) = pk;
            } else if (t == 3) {
                bf16x4 pk;
#pragma unroll
                for (int reg = 0; reg < 4; reg++)
                    pk[reg] = (__bf16)(1.0f / (1.0f + __expf(-(acc[mi][ni][reg] + bg_))));
                *(bf16x4*)(&wsgT[((size_t)(b2 * NH + h) * CC + c) * LQK + (mbase & 255)]) = pk;
            } else {
#pragma unroll
                for (int reg = 0; reg < 4; reg++) {
                    const int l = (mbase + reg) & 255;
                    float v = acc[mi][ni][reg];
                    size_t idx = ((size_t)(b2 * NH + h) * LQK + l) * CC + c;
                    if (t == 0) wsq[idx] = (__bf16)(v * 0.17677669529663689f);
                    else        wsk[idx] = (__bf16)v;
                }
            }
        }
    }
}

// ---------------- Kernel 2: attention (bias+K LDS staged; V,nbb in regs) --
// grid 4096; XCD head-grouping; 4 chunks of 64 k; stage = 5 gload_lds/wave
// {bias 4, K 1} dbuf; V+nbb reg-loaded BEFORE stage issue so their
// consumption waits vmcnt(5), leaving the stage in flight under compute.
// LDS 50.2 KB -> 3 blocks/CU (12 waves).
__global__ __launch_bounds__(256, 3) void k_attn(
    const __bf16* __restrict__ wsq, const __bf16* __restrict__ wsk,
    const __bf16* __restrict__ wsvT, const __bf16* __restrict__ wsgT,
    const float* __restrict__ bias, const float* __restrict__ nbb,
    __bf16* __restrict__ wswa)
{
    __shared__ float  Bl[2][64][64];    // 32 KB bias dbuf (linear)
    __shared__ __bf16 Kl[2][2048];      // 8 KB  K dbuf (swizzled units)
    __shared__ __bf16 P[4][16][TP];     // 9 KB wave-private P (16-B aligned)

    const int tid = threadIdx.x;
    // ---- XCD head-grouping swizzle ----
    const int u0 = blockIdx.x;
    const int xcd = u0 & 7, slot = u0 >> 3;
    const int head = xcd + 8 * (slot >> 2);
    const int qt = slot & 3;
    const int b2 = head >> 3, h = head & 7;

    const int lane = tid & 63, w = tid >> 6;
    const int g = lane >> 4, kg = g * 8, c0 = lane & 15;
    const int qbase = qt * 64 + w * 16;
    const int q = qbase + c0;
    const int rw = w * 16 + c0;               // q-row within block (0..63)

    const __bf16* qp = wsq + (size_t)(b2 * NH + h) * LQK * CC;
    const __bf16* kp = wsk + (size_t)(b2 * NH + h) * LQK * CC;
    const __bf16* vT = wsvT + (size_t)(b2 * NH + h) * CC * LQK;
    const __bf16* gT = wsgT + (size_t)(b2 * NH + h) * CC * LQK;
    const float* np = nbb + ((size_t)h * LQK + q) * LQK;
    const float* bblk = bias + ((size_t)(b2 * NH + h) * LQK + qt * 64) * LQK;

    // stage chunk c into buf: bias 16KB (4/wave) + K 4KB (1/wave)
    auto stage = [&](int buf, int c) {
        const int rbase = tid >> 4, jj = tid & 15;
#pragma unroll
        for (int i = 0; i < 4; i++) {
            const int row = i * 16 + rbase;                 // 0..63
            const int uu = jj ^ (row & 7);                  // src-unit swizzle
            gload_lds16(bblk + (size_t)row * LQK + c * 64 + uu * 4,
                        &Bl[buf][i * 16 + w * 4][0]);
        }
        {   // K: rows w*16+(lane>>2); unit swz (L&3)^((L>>3)&3)
            const int su = (lane & 3) ^ ((lane >> 3) & 3);
            gload_lds16(kp + (size_t)(c * 64 + w * 16 + (lane >> 2)) * CC + su * 8,
                        &Kl[buf][w * 512]);
        }
    };

    bf16x8 qf = *(const bf16x8*)(qp + (size_t)q * CC + kg);

    stage(0, 0);
    __syncthreads();

    float l = 0.0f;
    f32x4 o[2] = {};

#pragma unroll
    for (int c = 0; c < 4; c++) {
        const int cur = c & 1;

        // (1) V + nbb reg loads for THIS chunk (before stage: FIFO-clean)
        bf16x8 vf[4];
        f32x4 n4[4];
#pragma unroll
        for (int kt2 = 0; kt2 < 2; kt2++)
#pragma unroll
            for (int vn = 0; vn < 2; vn++)
                vf[kt2 * 2 + vn] = *(const bf16x8*)(
                    vT + (size_t)(vn * 16 + c0) * LQK + c * 64 + kt2 * 32 + kg);
#pragma unroll
        for (int j = 0; j < 4; j++)
            n4[j] = *(const f32x4*)(np + c * 64 + j * 16 + g * 4);
        __builtin_amdgcn_sched_barrier(0);

        // (2) async stage of NEXT chunk (5 gload_lds/wave, in flight to barrier)
        if (c < 3) stage(cur ^ 1, c + 1);
        __builtin_amdgcn_sched_barrier(0);

        // (3) compute chunk c: bias/K from LDS, V/nbb from regs (vmcnt(5))
        float csum = 0.0f;
#pragma unroll
        for (int j = 0; j < 4; j++) {
            const int su = ((j * 4 + g) ^ (rw & 7)) * 4;
            f32x4 b4 = *(const f32x4*)(&Bl[cur][rw][su]);
            bf16x8 kf = *(const bf16x8*)(
                &Kl[cur][((j * 16 + c0) * 4 + (g ^ ((c0 >> 1) & 3))) * 8]);
            f32x4 cc;
#pragma unroll
            for (int r2 = 0; r2 < 4; r2++) cc[r2] = b4[r2] + n4[j][r2];
            f32x4 s = MFMA16(kf, qf, cc, 0, 0, 0);
            bf16x4 pk;
#pragma unroll
            for (int r2 = 0; r2 < 4; r2++) {
                float e = __expf(s[r2]);      // no max-sub: |s| bounded ~20
                csum += e;
                pk[r2] = (__bf16)e;
            }
            *(bf16x4*)(&P[w][c0][j * 16 + g * 4]) = pk;
        }
        l += csum;
#pragma unroll
        for (int kt2 = 0; kt2 < 2; kt2++) {
            bf16x8 pa = *(const bf16x8*)(&P[w][c0][kt2 * 32 + kg]);
#pragma unroll
            for (int vn = 0; vn < 2; vn++)
                o[vn] = MFMA16(pa, vf[kt2 * 2 + vn], o[vn], 0, 0, 0);
        }
        if (c < 3) __syncthreads();           // drains stage(c+1); dbuf safety
    }

    l += __shfl_xor(l, 16);
    l += __shfl_xor(l, 32);
    const float inv = 1.0f / l;

    // ---- 1/sum, gate (transposed, bf16x4), store ----
#pragma unroll
    for (int vn = 0; vn < 2; vn++) {
        const int c = vn * 16 + c0;
        bf16x4 g4 = *(const bf16x4*)(gT + (size_t)c * LQK + qbase + g * 4);
#pragma unroll
        for (int reg = 0; reg < 4; reg++) {
            const int row = qbase + g * 4 + reg;
            const float invr = __shfl(inv, g * 4 + reg, 64);
            const float val = o[vn][reg] * invr * (float)g4[reg];
            wswa[((size_t)(b2 * LQK + row)) * (NH * CC) + h * CC + c] = (__bf16)val;
        }
    }
}

// ---------------- Kernel 3: output projection (tiled GEMM) ----------------
__global__ __launch_bounds__(256, 2) void k_out(
    const __bf16* __restrict__ wa, const __bf16* __restrict__ wBF,
    const float* __restrict__ bo, float* __restrict__ out)
{
    __shared__ __bf16 At[2][128][TP];
    __shared__ __bf16 Bt[2][128][TP];

    const int mb = blockIdx.x, nb = blockIdx.y;
    const __bf16* W = wBF + ((size_t)4 << 16) + (size_t)(nb * 128) * 256;

    const int tid = threadIdx.x;
    const int lane = tid & 63, w = tid >> 6;
    const int g = lane >> 4, kg = g * 8, c0 = lane & 15;
    const int mq = (w >> 1) * 64, nq = (w & 1) * 64;
    const int m0 = mb * 128;
    const int srow = tid >> 1, shalf = (tid & 1) * 32;

    f32x4 acc[4][4] = {};
    bf16x8 av[4], bv[4];
    auto load_stage = [&](int kit) {
        const __bf16* ap = wa + (size_t)(m0 + srow) * 256 + kit * 64 + shalf;
        const __bf16* bp = W + (size_t)srow * 256 + kit * 64 + shalf;
#pragma unroll
        for (int j = 0; j < 4; j++) {
            av[j] = *(const bf16x8*)(ap + j * 8);
            bv[j] = *(const bf16x8*)(bp + j * 8);
        }
    };
    auto write_stage = [&](int buf) {
#pragma unroll
        for (int j = 0; j < 4; j++) {
            *(bf16x8*)(&At[buf][srow][shalf + j * 8]) = av[j];
            *(bf16x8*)(&Bt[buf][srow][shalf + j * 8]) = bv[j];
        }
    };

    load_stage(0);
    write_stage(0);
    __syncthreads();

#pragma unroll
    for (int kit = 0; kit < 4; kit++) {
        if (kit < 3) load_stage(kit + 1);
        const int cur = kit & 1;
#pragma unroll
        for (int ks = 0; ks < 2; ks++) {
            bf16x8 af[4], bf_[4];
#pragma unroll
            for (int mi = 0; mi < 4; mi++)
                af[mi] = *(const bf16x8*)(&At[cur][mq + mi * 16 + c0][ks * 32 + kg]);
#pragma unroll
            for (int ni = 0; ni < 4; ni++)
                bf_[ni] = *(const bf16x8*)(&Bt[cur][nq + ni * 16 + c0][ks * 32 + kg]);
#pragma unroll
            for (int mi = 0; mi < 4; mi++)
#pragma unroll
                for (int ni = 0; ni < 4; ni++)
                    acc[mi][ni] = MFMA16(af[mi], bf_[ni], acc[mi][ni], 0, 0, 0);
        }
        if (kit < 3) write_stage(cur ^ 1);
        __syncthreads();
    }

#pragma unroll
    for (int ni = 0; ni < 4; ni++) {
        const int n = nb * 128 + nq + ni * 16 + c0;
        const float bo_ = bo[n];
#pragma unroll
        for (int mi = 0; mi < 4; mi++) {
            const int mbase = m0 + mq + mi * 16 + g * 4;
#pragma unroll
            for (int reg = 0; reg < 4; reg++)
                out[(size_t)(mbase + reg) * 256 + n] = acc[mi][ni][reg] + bo_;
        }
    }
}

// ---------------- launcher ------------------------------------------------
extern "C" void kernel_launch(void* const* d_in, const int* in_sizes, int n_in,
                              void* d_out, int out_size, void* d_ws, size_t ws_size,
                              hipStream_t stream) {
    const float* qd  = (const float*)d_in[0];
    const float* kvd = (const float*)d_in[1];
    const float* bias = (const float*)d_in[2];
    const float* nbb = (const float*)d_in[3];
    const float* Wq = (const float*)d_in[4];
    const float* Wk = (const float*)d_in[5];
    const float* Wv = (const float*)d_in[6];
    const float* Wg = (const float*)d_in[7];
    const float* bg = (const float*)d_in[8];
    const float* Wo = (const float*)d_in[9];
    const float* bo = (const float*)d_in[10];
    float* out = (float*)d_out;

    __bf16* ws = (__bf16*)d_ws;
    __bf16* wsq  = ws;
    __bf16* wsk  = wsq + NTOK;
    __bf16* wsvT = wsk + NTOK;
    __bf16* wsgT = wsvT + NTOK;
    __bf16* wBF  = wsgT + NTOK;            // 5 * 65536 bf16 weights
    __bf16* qbf  = wBF + 5 * 65536;        // activations bf16 (dead after k_proj)
    __bf16* kvbf = qbf + NTOK;
    __bf16* wswa = qbf;                    // alias: written by k_attn after k_proj

    k_cvt<<<dim3(8512), 256, 0, stream>>>(qd, kvd, Wq, Wk, Wv, Wg, Wo,
                                          qbf, kvbf, wBF);
    k_proj<<<dim3(256, 8), 256, 0, stream>>>(qbf, kvbf, wBF, bg,
                                             wsq, wsk, wsvT, wsgT);
    k_attn<<<dim3(4096), 256, 0, stream>>>(wsq, wsk, wsvT, wsgT, bias, nbb, wswa);
    k_out<<<dim3(256, 2), 256, 0, stream>>>(wswa, wBF, bo, out);
}

// Round 15
// 164.043 us; speedup vs baseline: 1.1164x; 1.0270x over previous
//
#include <hip/hip_runtime.h>
#include <hip/hip_bf16.h>

// dims
#define NB2 128
#define LQK 256
#define DIM 256
#define NH 8
#define CC 32

typedef __bf16 bf16x8 __attribute__((ext_vector_type(8)));
typedef __bf16 bf16x4 __attribute__((ext_vector_type(4)));
typedef float f32x4 __attribute__((ext_vector_type(4)));

#define MFMA16 __builtin_amdgcn_mfma_f32_16x16x32_bf16

// LDS tile row stride (bf16): 64 k + 8 pad (must stay ≡0 mod 8 elems: b128)
#define TP 72

#define NTOK ((size_t)NB2 * LQK * NH * CC)   // 8,388,608

// async global->LDS, 16B per lane; LDS dest is wave-uniform base + lane*16
static __device__ __forceinline__ void gload_lds16(const void* g, void* l) {
    __builtin_amdgcn_global_load_lds(
        (const __attribute__((address_space(1))) unsigned int*)g,
        (__attribute__((address_space(3))) unsigned int*)l,
        16, 0, 0);
}

// ---------------- Kernel 0: fp32 -> bf16 (activations + weights) ----------
__global__ __launch_bounds__(256) void k_cvt(
    const float* __restrict__ qd, const float* __restrict__ kvd,
    const float* __restrict__ Wq, const float* __restrict__ Wk,
    const float* __restrict__ Wv, const float* __restrict__ Wg,
    const float* __restrict__ Wo,
    __bf16* __restrict__ qbf, __bf16* __restrict__ kvbf,
    __bf16* __restrict__ wBF)
{
    const int b = blockIdx.x;
    if (b < 8192) {
        size_t i = ((size_t)b * 256 + threadIdx.x) * 8;
        const float* src;
        __bf16* dst;
        if (i < NTOK) { src = qd + i; dst = qbf + i; }
        else          { src = kvd + (i - NTOK); dst = kvbf + (i - NTOK); }
        f32x4 a = *(const f32x4*)src;
        f32x4 c = *(const f32x4*)(src + 4);
        bf16x8 r;
        r[0] = (__bf16)a[0]; r[1] = (__bf16)a[1]; r[2] = (__bf16)a[2]; r[3] = (__bf16)a[3];
        r[4] = (__bf16)c[0]; r[5] = (__bf16)c[1]; r[6] = (__bf16)c[2]; r[7] = (__bf16)c[3];
        *(bf16x8*)dst = r;
    } else {
        int i = ((b - 8192) * 256 + threadIdx.x) * 4;
        int mat = i >> 16;
        int off = i & 65535;
        const float* src = (mat == 0) ? Wq : (mat == 1) ? Wk : (mat == 2) ? Wv
                          : (mat == 3) ? Wg : Wo;
        f32x4 v = *(const f32x4*)(src + off);
        __bf16* d = wBF + ((size_t)mat << 16) + off;
        d[0] = (__bf16)v[0]; d[1] = (__bf16)v[1]; d[2] = (__bf16)v[2]; d[3] = (__bf16)v[3];
    }
}

// ---------------- Kernel 1: QKVG projection (tiled GEMM, bf16 A) ----------
__global__ __launch_bounds__(256, 2) void k_proj(
    const __bf16* __restrict__ qbf, const __bf16* __restrict__ kvbf,
    const __bf16* __restrict__ wBF, const float* __restrict__ bg,
    __bf16* __restrict__ wsq, __bf16* __restrict__ wsk,
    __bf16* __restrict__ wsvT, __bf16* __restrict__ wsgT)
{
    __shared__ __bf16 At[2][128][TP];
    __shared__ __bf16 Bt[2][128][TP];

    const int mb = blockIdx.x, nb = blockIdx.y;
    const int t = nb >> 1;                       // 0=q 1=k 2=v 3=g
    const __bf16* X = (t == 0 || t == 3) ? qbf : kvbf;
    const __bf16* W = wBF + ((size_t)t << 16) + (size_t)((nb & 1) * 128) * 256;

    const int tid = threadIdx.x;
    const int lane = tid & 63, w = tid >> 6;
    const int g = lane >> 4, kg = g * 8, c0 = lane & 15;
    const int mq = (w >> 1) * 64, nq = (w & 1) * 64;
    const int m0 = mb * 128;
    const int srow = tid >> 1, shalf = (tid & 1) * 32;

    f32x4 acc[4][4] = {};
    bf16x8 av[4], bv[4];
    auto load_stage = [&](int kit) {
        const __bf16* ap = X + (size_t)(m0 + srow) * DIM + kit * 64 + shalf;
        const __bf16* bp = W + (size_t)srow * 256 + kit * 64 + shalf;
#pragma unroll
        for (int j = 0; j < 4; j++) {
            av[j] = *(const bf16x8*)(ap + j * 8);
            bv[j] = *(const bf16x8*)(bp + j * 8);
        }
    };
    auto write_stage = [&](int buf) {
#pragma unroll
        for (int j = 0; j < 4; j++) {
            *(bf16x8*)(&At[buf][srow][shalf + j * 8]) = av[j];
            *(bf16x8*)(&Bt[buf][srow][shalf + j * 8]) = bv[j];
        }
    };

    load_stage(0);
    write_stage(0);
    __syncthreads();

#pragma unroll
    for (int kit = 0; kit < 4; kit++) {
        if (kit < 3) load_stage(kit + 1);
        const int cur = kit & 1;
#pragma unroll
        for (int ks = 0; ks < 2; ks++) {
            bf16x8 af[4], bf_[4];
#pragma unroll
            for (int mi = 0; mi < 4; mi++)
                af[mi] = *(const bf16x8*)(&At[cur][mq + mi * 16 + c0][ks * 32 + kg]);
#pragma unroll
            for (int ni = 0; ni < 4; ni++)
                bf_[ni] = *(const bf16x8*)(&Bt[cur][nq + ni * 16 + c0][ks * 32 + kg]);
#pragma unroll
            for (int mi = 0; mi < 4; mi++)
#pragma unroll
                for (int ni = 0; ni < 4; ni++)
                    acc[mi][ni] = MFMA16(af[mi], bf_[ni], acc[mi][ni], 0, 0, 0);
        }
        if (kit < 3) write_stage(cur ^ 1);
        __syncthreads();
    }

    // ---- epilogue ----
#pragma unroll
    for (int ni = 0; ni < 4; ni++) {
        const int nloc = (nb & 1) * 128 + nq + ni * 16 + c0;
        const int h = nloc >> 5, c = nloc & 31;
        const float bg_ = (t == 3) ? bg[nloc] : 0.0f;
#pragma unroll
        for (int mi = 0; mi < 4; mi++) {
            const int mbase = m0 + mq + mi * 16 + g * 4;
            const int b2 = mbase >> 8;
            if (t == 2) {
                bf16x4 pk;
#pragma unroll
                for (int reg = 0; reg < 4; reg++) pk[reg] = (__bf16)acc[mi][ni][reg];
                *(bf16x4*)(&wsvT[((size_t)(b2 * NH + h) * CC + c) * LQK + (mbase & 255)]) = pk;
            } else if (t == 3) {
                bf16x4 pk;
#pragma unroll
                for (int reg = 0; reg < 4; reg++)
                    pk[reg] = (__bf16)(1.0f / (1.0f + __expf(-(acc[mi][ni][reg] + bg_))));
                *(bf16x4*)(&wsgT[((size_t)(b2 * NH + h) * CC + c) * LQK + (mbase & 255)]) = pk;
            } else {
#pragma unroll
                for (int reg = 0; reg < 4; reg++) {
                    const int l = (mbase + reg) & 255;
                    float v = acc[mi][ni][reg];
                    size_t idx = ((size_t)(b2 * NH + h) * LQK + l) * CC + c;
                    if (t == 0) wsq[idx] = (__bf16)(v * 0.17677669529663689f);
                    else        wsk[idx] = (__bf16)v;
                }
            }
        }
    }
}

// ---------------- Kernel 2: attention (q-phased; full-row bias bursts) ----
// grid 4096; XCD head-grouping. 4 phases of 16 q-rows x all 256 k.
// Bias staged as 16 FULL 1-KB rows per phase (contiguous 16-KB stream).
// Wave w owns k-slice [w*64,w*64+64): QK^T+exp+P+PV wave-private; row-sum
// and O k-partials reduced via small LDS once per phase.
__global__ __launch_bounds__(256, 3) void k_attn(
    const __bf16* __restrict__ wsq, const __bf16* __restrict__ wsk,
    const __bf16* __restrict__ wsvT, const __bf16* __restrict__ wsgT,
    const float* __restrict__ bias, const float* __restrict__ nbb,
    __bf16* __restrict__ wswa)
{
    __shared__ float  Bl[2][16][256];   // 32 KB: 16 full bias rows, dbuf
    __shared__ __bf16 P[4][16][TP];     // 9 KB wave-private P (k-local 64)
    __shared__ float  lsum[4][16];      // row-sum partials
    __shared__ float  op[4][16][33];    // 8.25 KB O k-partials (padded)

    const int tid = threadIdx.x;
    // ---- XCD head-grouping swizzle ----
    const int u0 = blockIdx.x;
    const int xcd = u0 & 7, slot = u0 >> 3;
    const int head = xcd + 8 * (slot >> 2);
    const int qt = slot & 3;
    const int b2 = head >> 3, h = head & 7;

    const int lane = tid & 63, w = tid >> 6;
    const int g = lane >> 4, kg = g * 8, c0 = lane & 15;

    const __bf16* qp = wsq + (size_t)(b2 * NH + h) * LQK * CC;
    const __bf16* kp = wsk + (size_t)(b2 * NH + h) * LQK * CC;
    const __bf16* vT = wsvT + (size_t)(b2 * NH + h) * CC * LQK;
    const __bf16* gT = wsgT + (size_t)(b2 * NH + h) * CC * LQK;
    const float* npb = nbb + (size_t)h * LQK * LQK;
    const float* bblk = bias + ((size_t)(b2 * NH + h) * LQK + qt * 64) * LQK;

    // stage phase p's bias: 4 full rows per wave, each issue = one 1-KB row.
    // phys unit L holds src unit L^row (involution, row<16).
    auto stage = [&](int buf, int p) {
#pragma unroll
        for (int i = 0; i < 4; i++) {
            const int row = w * 4 + i;                     // 0..15 in phase
            gload_lds16(bblk + (size_t)(p * 16 + row) * LQK + ((lane ^ row) * 4),
                        &Bl[buf][row][0]);
        }
    };

    // K fragments are phase-invariant (wave's k-slice fixed): load once.
    bf16x8 kf[4], vf[4];
#pragma unroll
    for (int j = 0; j < 4; j++)
        kf[j] = *(const bf16x8*)(kp + (size_t)(w * 64 + j * 16 + c0) * CC + kg);
#pragma unroll
    for (int kt2 = 0; kt2 < 2; kt2++)
#pragma unroll
        for (int vn = 0; vn < 2; vn++)
            vf[kt2 * 2 + vn] = *(const bf16x8*)(
                vT + (size_t)(vn * 16 + c0) * LQK + w * 64 + kt2 * 32 + kg);

    stage(0, 0);
    __syncthreads();

#pragma unroll
    for (int p = 0; p < 4; p++) {
        const int cur = p & 1;
        const int qglob = qt * 64 + p * 16 + c0;    // this lane's q-row

        // (1) per-phase reg loads (before stage: FIFO-clean)
        bf16x8 qf = *(const bf16x8*)(qp + (size_t)qglob * CC + kg);
        f32x4 nb4[4];
#pragma unroll
        for (int j = 0; j < 4; j++)
            nb4[j] = *(const f32x4*)(npb + (size_t)qglob * LQK + w * 64 + j * 16 + g * 4);
        __builtin_amdgcn_sched_barrier(0);

        // (2) async stage of next phase's 16 bias rows
        if (p < 3) stage(cur ^ 1, p + 1);
        __builtin_amdgcn_sched_barrier(0);

        // (3) QK^T + exp + P strip + partial row-sum (wave k-slice)
        float csum = 0.0f;
#pragma unroll
        for (int j = 0; j < 4; j++) {
            f32x4 b4 = *(const f32x4*)(&Bl[cur][c0][(w * 16 + ((j * 4 + g) ^ c0)) * 4]);
            f32x4 cc;
#pragma unroll
            for (int r2 = 0; r2 < 4; r2++) cc[r2] = b4[r2] + nb4[j][r2];
            f32x4 s = MFMA16(kf[j], qf, cc, 0, 0, 0);
            bf16x4 pk;
#pragma unroll
            for (int r2 = 0; r2 < 4; r2++) {
                float e = __expf(s[r2]);      // no max-sub: |s| bounded ~20
                csum += e;
                pk[r2] = (__bf16)e;
            }
            *(bf16x4*)(&P[w][c0][j * 16 + g * 4]) = pk;
        }
        csum += __shfl_xor(csum, 16);
        csum += __shfl_xor(csum, 32);
        if (lane < 16) lsum[w][lane] = csum;

        // (4) PV over wave k-slice -> O partials
        f32x4 o2[2] = {};
#pragma unroll
        for (int kt2 = 0; kt2 < 2; kt2++) {
            bf16x8 pa = *(const bf16x8*)(&P[w][c0][kt2 * 32 + kg]);
#pragma unroll
            for (int vn = 0; vn < 2; vn++)
                o2[vn] = MFMA16(pa, vf[kt2 * 2 + vn], o2[vn], 0, 0, 0);
        }
#pragma unroll
        for (int vn = 0; vn < 2; vn++)
#pragma unroll
            for (int r2 = 0; r2 < 4; r2++)
                op[w][g * 4 + r2][vn * 16 + c0] = o2[vn][r2];

        __syncthreads();

        // (5) cross-wave reduce + gate + store: 512 outs / 256 thr = 2 each
        {
            const int idx = tid * 2;
            const int qr = idx >> 5;              // 0..15
            const int cbase = idx & 31;           // even
            const int qg = qt * 64 + p * 16 + qr;
            const float li = 1.0f / (lsum[0][qr] + lsum[1][qr] + lsum[2][qr] + lsum[3][qr]);
#pragma unroll
            for (int e = 0; e < 2; e++) {
                const int cc2 = cbase + e;
                float val = op[0][qr][cc2] + op[1][qr][cc2] + op[2][qr][cc2] + op[3][qr][cc2];
                val *= li * (float)gT[(size_t)cc2 * LQK + qg];
                wswa[((size_t)(b2 * LQK + qg)) * (NH * CC) + h * CC + cc2] = (__bf16)val;
            }
        }
        __syncthreads();    // op/lsum reuse safety + drains stage(p+1)
    }
}

// ---------------- Kernel 3: output projection (tiled GEMM) ----------------
__global__ __launch_bounds__(256, 2) void k_out(
    const __bf16* __restrict__ wa, const __bf16* __restrict__ wBF,
    const float* __restrict__ bo, float* __restrict__ out)
{
    __shared__ __bf16 At[2][128][TP];
    __shared__ __bf16 Bt[2][128][TP];

    const int mb = blockIdx.x, nb = blockIdx.y;
    const __bf16* W = wBF + ((size_t)4 << 16) + (size_t)(nb * 128) * 256;

    const int tid = threadIdx.x;
    const int lane = tid & 63, w = tid >> 6;
    const int g = lane >> 4, kg = g * 8, c0 = lane & 15;
    const int mq = (w >> 1) * 64, nq = (w & 1) * 64;
    const int m0 = mb * 128;
    const int srow = tid >> 1, shalf = (tid & 1) * 32;

    f32x4 acc[4][4] = {};
    bf16x8 av[4], bv[4];
    auto load_stage = [&](int kit) {
        const __bf16* ap = wa + (size_t)(m0 + srow) * 256 + kit * 64 + shalf;
        const __bf16* bp = W + (size_t)srow * 256 + kit * 64 + shalf;
#pragma unroll
        for (int j = 0; j < 4; j++) {
            av[j] = *(const bf16x8*)(ap + j * 8);
            bv[j] = *(const bf16x8*)(bp + j * 8);
        }
    };
    auto write_stage = [&](int buf) {
#pragma unroll
        for (int j = 0; j < 4; j++) {
            *(bf16x8*)(&At[buf][srow][shalf + j * 8]) = av[j];
            *(bf16x8*)(&Bt[buf][srow][shalf + j * 8]) = bv[j];
        }
    };

    load_stage(0);
    write_stage(0);
    __syncthreads();

#pragma unroll
    for (int kit = 0; kit < 4; kit++) {
        if (kit < 3) load_stage(kit + 1);
        const int cur = kit & 1;
#pragma unroll
        for (int ks = 0; ks < 2; ks++) {
            bf16x8 af[4], bf_[4];
#pragma unroll
            for (int mi = 0; mi < 4; mi++)
                af[mi] = *(const bf16x8*)(&At[cur][mq + mi * 16 + c0][ks * 32 + kg]);
#pragma unroll
            for (int ni = 0; ni < 4; ni++)
                bf_[ni] = *(const bf16x8*)(&Bt[cur][nq + ni * 16 + c0][ks * 32 + kg]);
#pragma unroll
            for (int mi = 0; mi < 4; mi++)
#pragma unroll
                for (int ni = 0; ni < 4; ni++)
                    acc[mi][ni] = MFMA16(af[mi], bf_[ni], acc[mi][ni], 0, 0, 0);
        }
        if (kit < 3) write_stage(cur ^ 1);
        __syncthreads();
    }

#pragma unroll
    for (int ni = 0; ni < 4; ni++) {
        const int n = nb * 128 + nq + ni * 16 + c0;
        const float bo_ = bo[n];
#pragma unroll
        for (int mi = 0; mi < 4; mi++) {
            const int mbase = m0 + mq + mi * 16 + g * 4;
#pragma unroll
            for (int reg = 0; reg < 4; reg++)
                out[(size_t)(mbase + reg) * 256 + n] = acc[mi][ni][reg] + bo_;
        }
    }
}

// ---------------- launcher ------------------------------------------------
extern "C" void kernel_launch(void* const* d_in, const int* in_sizes, int n_in,
                              void* d_out, int out_size, void* d_ws, size_t ws_size,
                              hipStream_t stream) {
    const float* qd  = (const float*)d_in[0];
    const float* kvd = (const float*)d_in[1];
    const float* bias = (const float*)d_in[2];
    const float* nbb = (const float*)d_in[3];
    const float* Wq = (const float*)d_in[4];
    const float* Wk = (const float*)d_in[5];
    const float* Wv = (const float*)d_in[6];
    const float* Wg = (const float*)d_in[7];
    const float* bg = (const float*)d_in[8];
    const float* Wo = (const float*)d_in[9];
    const float* bo = (const float*)d_in[10];
    float* out = (float*)d_out;

    __bf16* ws = (__bf16*)d_ws;
    __bf16* wsq  = ws;
    __bf16* wsk  = wsq + NTOK;
    __bf16* wsvT = wsk + NTOK;
    __bf16* wsgT = wsvT + NTOK;
    __bf16* wBF  = wsgT + NTOK;            // 5 * 65536 bf16 weights
    __bf16* qbf  = wBF + 5 * 65536;        // activations bf16 (dead after k_proj)
    __bf16* kvbf = qbf + NTOK;
    __bf16* wswa = qbf;                    // alias: written by k_attn after k_proj

    k_cvt<<<dim3(8512), 256, 0, stream>>>(qd, kvd, Wq, Wk, Wv, Wg, Wo,
                                          qbf, kvbf, wBF);
    k_proj<<<dim3(256, 8), 256, 0, stream>>>(qbf, kvbf, wBF, bg,
                                             wsq, wsk, wsvT, wsgT);
    k_attn<<<dim3(4096), 256, 0, stream>>>(wsq, wsk, wsvT, wsgT, bias, nbb, wswa);
    k_out<<<dim3(256, 2), 256, 0, stream>>>(wswa, wBF, bo, out);
}

// Round 16
// 160.344 us; speedup vs baseline: 1.1422x; 1.0231x over previous
//
#include <hip/hip_runtime.h>
#include <hip/hip_bf16.h>

// dims
#define NB2 128
#define LQK 256
#define DIM 256
#define NH 8
#define CC 32

typedef __bf16 bf16x8 __attribute__((ext_vector_type(8)));
typedef __bf16 bf16x4 __attribute__((ext_vector_type(4)));
typedef float f32x4 __attribute__((ext_vector_type(4)));

#define MFMA16 __builtin_amdgcn_mfma_f32_16x16x32_bf16

// LDS tile row stride (bf16) for k_attn P: must stay ≡0 mod 8 elems (b128)
#define TP 72

#define NTOK ((size_t)NB2 * LQK * NH * CC)   // 8,388,608

// async global->LDS, 16B per lane; LDS dest is wave-uniform base + lane*16
static __device__ __forceinline__ void gload_lds16(const void* g, void* l) {
    __builtin_amdgcn_global_load_lds(
        (const __attribute__((address_space(1))) unsigned int*)g,
        (__attribute__((address_space(3))) unsigned int*)l,
        16, 0, 0);
}

// ---------------- Kernel 0: fp32 -> bf16 (activations + weights) ----------
__global__ __launch_bounds__(256) void k_cvt(
    const float* __restrict__ qd, const float* __restrict__ kvd,
    const float* __restrict__ Wq, const float* __restrict__ Wk,
    const float* __restrict__ Wv, const float* __restrict__ Wg,
    const float* __restrict__ Wo,
    __bf16* __restrict__ qbf, __bf16* __restrict__ kvbf,
    __bf16* __restrict__ wBF)
{
    const int b = blockIdx.x;
    if (b < 8192) {
        size_t i = ((size_t)b * 256 + threadIdx.x) * 8;
        const float* src;
        __bf16* dst;
        if (i < NTOK) { src = qd + i; dst = qbf + i; }
        else          { src = kvd + (i - NTOK); dst = kvbf + (i - NTOK); }
        f32x4 a = *(const f32x4*)src;
        f32x4 c = *(const f32x4*)(src + 4);
        bf16x8 r;
        r[0] = (__bf16)a[0]; r[1] = (__bf16)a[1]; r[2] = (__bf16)a[2]; r[3] = (__bf16)a[3];
        r[4] = (__bf16)c[0]; r[5] = (__bf16)c[1]; r[6] = (__bf16)c[2]; r[7] = (__bf16)c[3];
        *(bf16x8*)dst = r;
    } else {
        int i = ((b - 8192) * 256 + threadIdx.x) * 4;
        int mat = i >> 16;
        int off = i & 65535;
        const float* src = (mat == 0) ? Wq : (mat == 1) ? Wk : (mat == 2) ? Wv
                          : (mat == 3) ? Wg : Wo;
        f32x4 v = *(const f32x4*)(src + off);
        __bf16* d = wBF + ((size_t)mat << 16) + off;
        d[0] = (__bf16)v[0]; d[1] = (__bf16)v[1]; d[2] = (__bf16)v[2]; d[3] = (__bf16)v[3];
    }
}

// ---------------- Kernel 1: QKVG projection (gload_lds GEMM) --------------
// M=32768, N=1024=[q|k|v|g], K=256. grid (256,8), 256 thr (4 waves).
// 128x128 tile, BK=64 dbuf. LDS linear [128][64] bf16; staged via
// global_load_lds with both-sides XOR swizzle (src unit lu^(row&7),
// read phys ((ks*4+g)^(c0&7))) -> <=2-way bank conflicts.
__global__ __launch_bounds__(256, 2) void k_proj(
    const __bf16* __restrict__ qbf, const __bf16* __restrict__ kvbf,
    const __bf16* __restrict__ wBF, const float* __restrict__ bg,
    __bf16* __restrict__ wsq, __bf16* __restrict__ wsk,
    __bf16* __restrict__ wsvT, __bf16* __restrict__ wsgT)
{
    __shared__ __bf16 At[2][128 * 64];
    __shared__ __bf16 Bt[2][128 * 64];

    const int mb = blockIdx.x, nb = blockIdx.y;
    const int t = nb >> 1;                       // 0=q 1=k 2=v 3=g
    const __bf16* X = (t == 0 || t == 3) ? qbf : kvbf;
    const __bf16* W = wBF + ((size_t)t << 16) + (size_t)((nb & 1) * 128) * 256;

    const int tid = threadIdx.x;
    const int lane = tid & 63, w = tid >> 6;
    const int g = lane >> 4, c0 = lane & 15;
    const int mq = (w >> 1) * 64, nq = (w & 1) * 64;
    const int m0 = mb * 128;
    const int lrow = lane >> 3, lu = lane & 7;   // staging row-sub / unit

    // stage K-tile kt into buf: 4 A + 4 B block-wide gload_lds issues
    auto stage = [&](int buf, int kt) {
#pragma unroll
        for (int i = 0; i < 4; i++) {
            const int rr = i * 32 + w * 8 + lrow;          // 0..127
            const int su = lu ^ (rr & 7);                  // src-unit swizzle
            gload_lds16(X + (size_t)(m0 + rr) * 256 + kt * 64 + su * 8,
                        &At[buf][(i * 4 + w) * 512]);
        }
#pragma unroll
        for (int i = 0; i < 4; i++) {
            const int rr = i * 32 + w * 8 + lrow;
            const int su = lu ^ (rr & 7);
            gload_lds16(W + (size_t)rr * 256 + kt * 64 + su * 8,
                        &Bt[buf][(i * 4 + w) * 512]);
        }
    };

    f32x4 acc[4][4] = {};
    stage(0, 0);
    __syncthreads();

#pragma unroll
    for (int kt = 0; kt < 4; kt++) {
        const int cur = kt & 1;
        if (kt < 3) stage(cur ^ 1, kt + 1);      // async; drains at barrier
#pragma unroll
        for (int ks = 0; ks < 2; ks++) {
            const int px = ((ks * 4 + g) ^ (c0 & 7)) * 8;  // phys unit offset
            bf16x8 af[4], bf_[4];
#pragma unroll
            for (int mi = 0; mi < 4; mi++)
                af[mi] = *(const bf16x8*)(&At[cur][(mq + mi * 16 + c0) * 64 + px]);
#pragma unroll
            for (int ni = 0; ni < 4; ni++)
                bf_[ni] = *(const bf16x8*)(&Bt[cur][(nq + ni * 16 + c0) * 64 + px]);
#pragma unroll
            for (int mi = 0; mi < 4; mi++)
#pragma unroll
                for (int ni = 0; ni < 4; ni++)
                    acc[mi][ni] = MFMA16(af[mi], bf_[ni], acc[mi][ni], 0, 0, 0);
        }
        __syncthreads();
    }

    // ---- epilogue ----
#pragma unroll
    for (int ni = 0; ni < 4; ni++) {
        const int nloc = (nb & 1) * 128 + nq + ni * 16 + c0;
        const int h = nloc >> 5, c = nloc & 31;
        const float bg_ = (t == 3) ? bg[nloc] : 0.0f;
#pragma unroll
        for (int mi = 0; mi < 4; mi++) {
            const int mbase = m0 + mq + mi * 16 + g * 4;
            const int b2 = mbase >> 8;
            if (t == 2) {
                bf16x4 pk;
#pragma unroll
                for (int reg = 0; reg < 4; reg++) pk[reg] = (__bf16)acc[mi][ni][reg];
                *(bf16x4*)(&wsvT[((size_t)(b2 * NH + h) * CC + c) * LQK + (mbase & 255)]) = pk;
            } else if (t == 3) {
                bf16x4 pk;
#pragma unroll
                for (int reg = 0; reg < 4; reg++)
                    pk[reg] = (__bf16)(1.0f / (1.0f + __expf(-(acc[mi][ni][reg] + bg_))));
                *(bf16x4*)(&wsgT[((size_t)(b2 * NH + h) * CC + c) * LQK + (mbase & 255)]) = pk;
            } else {
#pragma unroll
                for (int reg = 0; reg < 4; reg++) {
                    const int l = (mbase + reg) & 255;
                    float v = acc[mi][ni][reg];
                    size_t idx = ((size_t)(b2 * NH + h) * LQK + l) * CC + c;
                    if (t == 0) wsq[idx] = (__bf16)(v * 0.17677669529663689f);
                    else        wsk[idx] = (__bf16)v;
                }
            }
        }
    }
}

// ---------------- Kernel 2: attention (q-phased; full-row bias bursts) ----
// (unchanged from round 15)
__global__ __launch_bounds__(256, 3) void k_attn(
    const __bf16* __restrict__ wsq, const __bf16* __restrict__ wsk,
    const __bf16* __restrict__ wsvT, const __bf16* __restrict__ wsgT,
    const float* __restrict__ bias, const float* __restrict__ nbb,
    __bf16* __restrict__ wswa)
{
    __shared__ float  Bl[2][16][256];   // 32 KB: 16 full bias rows, dbuf
    __shared__ __bf16 P[4][16][TP];     // 9 KB wave-private P (k-local 64)
    __shared__ float  lsum[4][16];      // row-sum partials
    __shared__ float  op[4][16][33];    // 8.25 KB O k-partials (padded)

    const int tid = threadIdx.x;
    const int u0 = blockIdx.x;
    const int xcd = u0 & 7, slot = u0 >> 3;
    const int head = xcd + 8 * (slot >> 2);
    const int qt = slot & 3;
    const int b2 = head >> 3, h = head & 7;

    const int lane = tid & 63, w = tid >> 6;
    const int g = lane >> 4, kg = g * 8, c0 = lane & 15;

    const __bf16* qp = wsq + (size_t)(b2 * NH + h) * LQK * CC;
    const __bf16* kp = wsk + (size_t)(b2 * NH + h) * LQK * CC;
    const __bf16* vT = wsvT + (size_t)(b2 * NH + h) * CC * LQK;
    const __bf16* gT = wsgT + (size_t)(b2 * NH + h) * CC * LQK;
    const float* npb = nbb + (size_t)h * LQK * LQK;
    const float* bblk = bias + ((size_t)(b2 * NH + h) * LQK + qt * 64) * LQK;

    auto stage = [&](int buf, int p) {
#pragma unroll
        for (int i = 0; i < 4; i++) {
            const int row = w * 4 + i;                     // 0..15 in phase
            gload_lds16(bblk + (size_t)(p * 16 + row) * LQK + ((lane ^ row) * 4),
                        &Bl[buf][row][0]);
        }
    };

    bf16x8 kf[4], vf[4];
#pragma unroll
    for (int j = 0; j < 4; j++)
        kf[j] = *(const bf16x8*)(kp + (size_t)(w * 64 + j * 16 + c0) * CC + kg);
#pragma unroll
    for (int kt2 = 0; kt2 < 2; kt2++)
#pragma unroll
        for (int vn = 0; vn < 2; vn++)
            vf[kt2 * 2 + vn] = *(const bf16x8*)(
                vT + (size_t)(vn * 16 + c0) * LQK + w * 64 + kt2 * 32 + kg);

    stage(0, 0);
    __syncthreads();

#pragma unroll
    for (int p = 0; p < 4; p++) {
        const int cur = p & 1;
        const int qglob = qt * 64 + p * 16 + c0;

        bf16x8 qf = *(const bf16x8*)(qp + (size_t)qglob * CC + kg);
        f32x4 nb4[4];
#pragma unroll
        for (int j = 0; j < 4; j++)
            nb4[j] = *(const f32x4*)(npb + (size_t)qglob * LQK + w * 64 + j * 16 + g * 4);
        __builtin_amdgcn_sched_barrier(0);

        if (p < 3) stage(cur ^ 1, p + 1);
        __builtin_amdgcn_sched_barrier(0);

        float csum = 0.0f;
#pragma unroll
        for (int j = 0; j < 4; j++) {
            f32x4 b4 = *(const f32x4*)(&Bl[cur][c0][(w * 16 + ((j * 4 + g) ^ c0)) * 4]);
            f32x4 cc;
#pragma unroll
            for (int r2 = 0; r2 < 4; r2++) cc[r2] = b4[r2] + nb4[j][r2];
            f32x4 s = MFMA16(kf[j], qf, cc, 0, 0, 0);
            bf16x4 pk;
#pragma unroll
            for (int r2 = 0; r2 < 4; r2++) {
                float e = __expf(s[r2]);      // no max-sub: |s| bounded ~20
                csum += e;
                pk[r2] = (__bf16)e;
            }
            *(bf16x4*)(&P[w][c0][j * 16 + g * 4]) = pk;
        }
        csum += __shfl_xor(csum, 16);
        csum += __shfl_xor(csum, 32);
        if (lane < 16) lsum[w][lane] = csum;

        f32x4 o2[2] = {};
#pragma unroll
        for (int kt2 = 0; kt2 < 2; kt2++) {
            bf16x8 pa = *(const bf16x8*)(&P[w][c0][kt2 * 32 + kg]);
#pragma unroll
            for (int vn = 0; vn < 2; vn++)
                o2[vn] = MFMA16(pa, vf[kt2 * 2 + vn], o2[vn], 0, 0, 0);
        }
#pragma unroll
        for (int vn = 0; vn < 2; vn++)
#pragma unroll
            for (int r2 = 0; r2 < 4; r2++)
                op[w][g * 4 + r2][vn * 16 + c0] = o2[vn][r2];

        __syncthreads();

        {
            const int idx = tid * 2;
            const int qr = idx >> 5;
            const int cbase = idx & 31;
            const int qg = qt * 64 + p * 16 + qr;
            const float li = 1.0f / (lsum[0][qr] + lsum[1][qr] + lsum[2][qr] + lsum[3][qr]);
#pragma unroll
            for (int e = 0; e < 2; e++) {
                const int cc2 = cbase + e;
                float val = op[0][qr][cc2] + op[1][qr][cc2] + op[2][qr][cc2] + op[3][qr][cc2];
                val *= li * (float)gT[(size_t)cc2 * LQK + qg];
                wswa[((size_t)(b2 * LQK + qg)) * (NH * CC) + h * CC + cc2] = (__bf16)val;
            }
        }
        __syncthreads();
    }
}

// ---------------- Kernel 3: output projection (gload_lds GEMM) ------------
// M=32768, N=256, K=256. grid (256,2). Same structure as k_proj.
__global__ __launch_bounds__(256, 2) void k_out(
    const __bf16* __restrict__ wa, const __bf16* __restrict__ wBF,
    const float* __restrict__ bo, float* __restrict__ out)
{
    __shared__ __bf16 At[2][128 * 64];
    __shared__ __bf16 Bt[2][128 * 64];

    const int mb = blockIdx.x, nb = blockIdx.y;
    const __bf16* W = wBF + ((size_t)4 << 16) + (size_t)(nb * 128) * 256;

    const int tid = threadIdx.x;
    const int lane = tid & 63, w = tid >> 6;
    const int g = lane >> 4, c0 = lane & 15;
    const int mq = (w >> 1) * 64, nq = (w & 1) * 64;
    const int m0 = mb * 128;
    const int lrow = lane >> 3, lu = lane & 7;

    auto stage = [&](int buf, int kt) {
#pragma unroll
        for (int i = 0; i < 4; i++) {
            const int rr = i * 32 + w * 8 + lrow;
            const int su = lu ^ (rr & 7);
            gload_lds16(wa + (size_t)(m0 + rr) * 256 + kt * 64 + su * 8,
                        &At[buf][(i * 4 + w) * 512]);
        }
#pragma unroll
        for (int i = 0; i < 4; i++) {
            const int rr = i * 32 + w * 8 + lrow;
            const int su = lu ^ (rr & 7);
            gload_lds16(W + (size_t)rr * 256 + kt * 64 + su * 8,
                        &Bt[buf][(i * 4 + w) * 512]);
        }
    };

    f32x4 acc[4][4] = {};
    stage(0, 0);
    __syncthreads();

#pragma unroll
    for (int kt = 0; kt < 4; kt++) {
        const int cur = kt & 1;
        if (kt < 3) stage(cur ^ 1, kt + 1);
#pragma unroll
        for (int ks = 0; ks < 2; ks++) {
            const int px = ((ks * 4 + g) ^ (c0 & 7)) * 8;
            bf16x8 af[4], bf_[4];
#pragma unroll
            for (int mi = 0; mi < 4; mi++)
                af[mi] = *(const bf16x8*)(&At[cur][(mq + mi * 16 + c0) * 64 + px]);
#pragma unroll
            for (int ni = 0; ni < 4; ni++)
                bf_[ni] = *(const bf16x8*)(&Bt[cur][(nq + ni * 16 + c0) * 64 + px]);
#pragma unroll
            for (int mi = 0; mi < 4; mi++)
#pragma unroll
                for (int ni = 0; ni < 4; ni++)
                    acc[mi][ni] = MFMA16(af[mi], bf_[ni], acc[mi][ni], 0, 0, 0);
        }
        __syncthreads();
    }

#pragma unroll
    for (int ni = 0; ni < 4; ni++) {
        const int n = nb * 128 + nq + ni * 16 + c0;
        const float bo_ = bo[n];
#pragma unroll
        for (int mi = 0; mi < 4; mi++) {
            const int mbase = m0 + mq + mi * 16 + g * 4;
#pragma unroll
            for (int reg = 0; reg < 4; reg++)
                out[(size_t)(mbase + reg) * 256 + n] = acc[mi][ni][reg] + bo_;
        }
    }
}

// ---------------- launcher ------------------------------------------------
extern "C" void kernel_launch(void* const* d_in, const int* in_sizes, int n_in,
                              void* d_out, int out_size, void* d_ws, size_t ws_size,
                              hipStream_t stream) {
    const float* qd  = (const float*)d_in[0];
    const float* kvd = (const float*)d_in[1];
    const float* bias = (const float*)d_in[2];
    const float* nbb = (const float*)d_in[3];
    const float* Wq = (const float*)d_in[4];
    const float* Wk = (const float*)d_in[5];
    const float* Wv = (const float*)d_in[6];
    const float* Wg = (const float*)d_in[7];
    const float* bg = (const float*)d_in[8];
    const float* Wo = (const float*)d_in[9];
    const float* bo = (const float*)d_in[10];
    float* out = (float*)d_out;

    __bf16* ws = (__bf16*)d_ws;
    __bf16* wsq  = ws;
    __bf16* wsk  = wsq + NTOK;
    __bf16* wsvT = wsk + NTOK;
    __bf16* wsgT = wsvT + NTOK;
    __bf16* wBF  = wsgT + NTOK;            // 5 * 65536 bf16 weights
    __bf16* qbf  = wBF + 5 * 65536;        // activations bf16 (dead after k_proj)
    __bf16* kvbf = qbf + NTOK;
    __bf16* wswa = qbf;                    // alias: written by k_attn after k_proj

    k_cvt<<<dim3(8512), 256, 0, stream>>>(qd, kvd, Wq, Wk, Wv, Wg, Wo,
                                          qbf, kvbf, wBF);
    k_proj<<<dim3(256, 8), 256, 0, stream>>>(qbf, kvbf, wBF, bg,
                                             wsq, wsk, wsvT, wsgT);
    k_attn<<<dim3(4096), 256, 0, stream>>>(wsq, wsk, wsvT, wsgT, bias, nbb, wswa);
    k_out<<<dim3(256, 2), 256, 0, stream>>>(wswa, wBF, bo, out);
}

// Round 17
// 158.905 us; speedup vs baseline: 1.1525x; 1.0091x over previous
//
#include <hip/hip_runtime.h>
#include <hip/hip_bf16.h>

// dims
#define NB2 128
#define LQK 256
#define DIM 256
#define NH 8
#define CC 32

typedef __bf16 bf16x8 __attribute__((ext_vector_type(8)));
typedef __bf16 bf16x4 __attribute__((ext_vector_type(4)));
typedef float f32x4 __attribute__((ext_vector_type(4)));

#define MFMA16 __builtin_amdgcn_mfma_f32_16x16x32_bf16

// LDS tile row stride (bf16) for k_attn P: must stay ≡0 mod 8 elems (b128)
#define TP 72

#define NTOK ((size_t)NB2 * LQK * NH * CC)   // 8,388,608

// async global->LDS, 16B per lane; LDS dest is wave-uniform base + lane*16
static __device__ __forceinline__ void gload_lds16(const void* g, void* l) {
    __builtin_amdgcn_global_load_lds(
        (const __attribute__((address_space(1))) unsigned int*)g,
        (__attribute__((address_space(3))) unsigned int*)l,
        16, 0, 0);
}

// ---------------- Kernel 0: fp32 -> bf16 (activations + weights) ----------
__global__ __launch_bounds__(256) void k_cvt(
    const float* __restrict__ qd, const float* __restrict__ kvd,
    const float* __restrict__ Wq, const float* __restrict__ Wk,
    const float* __restrict__ Wv, const float* __restrict__ Wg,
    const float* __restrict__ Wo,
    __bf16* __restrict__ qbf, __bf16* __restrict__ kvbf,
    __bf16* __restrict__ wBF)
{
    const int b = blockIdx.x;
    if (b < 8192) {
        size_t i = ((size_t)b * 256 + threadIdx.x) * 8;
        const float* src;
        __bf16* dst;
        if (i < NTOK) { src = qd + i; dst = qbf + i; }
        else          { src = kvd + (i - NTOK); dst = kvbf + (i - NTOK); }
        f32x4 a = *(const f32x4*)src;
        f32x4 c = *(const f32x4*)(src + 4);
        bf16x8 r;
        r[0] = (__bf16)a[0]; r[1] = (__bf16)a[1]; r[2] = (__bf16)a[2]; r[3] = (__bf16)a[3];
        r[4] = (__bf16)c[0]; r[5] = (__bf16)c[1]; r[6] = (__bf16)c[2]; r[7] = (__bf16)c[3];
        *(bf16x8*)dst = r;
    } else {
        int i = ((b - 8192) * 256 + threadIdx.x) * 4;
        int mat = i >> 16;
        int off = i & 65535;
        const float* src = (mat == 0) ? Wq : (mat == 1) ? Wk : (mat == 2) ? Wv
                          : (mat == 3) ? Wg : Wo;
        f32x4 v = *(const f32x4*)(src + off);
        __bf16* d = wBF + ((size_t)mat << 16) + off;
        d[0] = (__bf16)v[0]; d[1] = (__bf16)v[1]; d[2] = (__bf16)v[2]; d[3] = (__bf16)v[3];
    }
}

// ---------------- Kernel 1: QKVG projection (gload_lds GEMM) --------------
__global__ __launch_bounds__(256, 2) void k_proj(
    const __bf16* __restrict__ qbf, const __bf16* __restrict__ kvbf,
    const __bf16* __restrict__ wBF, const float* __restrict__ bg,
    __bf16* __restrict__ wsq, __bf16* __restrict__ wsk,
    __bf16* __restrict__ wsvT, __bf16* __restrict__ wsgT)
{
    __shared__ __bf16 At[2][128 * 64];
    __shared__ __bf16 Bt[2][128 * 64];

    const int mb = blockIdx.x, nb = blockIdx.y;
    const int t = nb >> 1;                       // 0=q 1=k 2=v 3=g
    const __bf16* X = (t == 0 || t == 3) ? qbf : kvbf;
    const __bf16* W = wBF + ((size_t)t << 16) + (size_t)((nb & 1) * 128) * 256;

    const int tid = threadIdx.x;
    const int lane = tid & 63, w = tid >> 6;
    const int g = lane >> 4, c0 = lane & 15;
    const int mq = (w >> 1) * 64, nq = (w & 1) * 64;
    const int m0 = mb * 128;
    const int lrow = lane >> 3, lu = lane & 7;   // staging row-sub / unit

    auto stage = [&](int buf, int kt) {
#pragma unroll
        for (int i = 0; i < 4; i++) {
            const int rr = i * 32 + w * 8 + lrow;          // 0..127
            const int su = lu ^ (rr & 7);                  // src-unit swizzle
            gload_lds16(X + (size_t)(m0 + rr) * 256 + kt * 64 + su * 8,
                        &At[buf][(i * 4 + w) * 512]);
        }
#pragma unroll
        for (int i = 0; i < 4; i++) {
            const int rr = i * 32 + w * 8 + lrow;
            const int su = lu ^ (rr & 7);
            gload_lds16(W + (size_t)rr * 256 + kt * 64 + su * 8,
                        &Bt[buf][(i * 4 + w) * 512]);
        }
    };

    f32x4 acc[4][4] = {};
    stage(0, 0);
    __syncthreads();

#pragma unroll
    for (int kt = 0; kt < 4; kt++) {
        const int cur = kt & 1;
        if (kt < 3) stage(cur ^ 1, kt + 1);      // async; drains at barrier
#pragma unroll
        for (int ks = 0; ks < 2; ks++) {
            const int px = ((ks * 4 + g) ^ (c0 & 7)) * 8;  // phys unit offset
            bf16x8 af[4], bf_[4];
#pragma unroll
            for (int mi = 0; mi < 4; mi++)
                af[mi] = *(const bf16x8*)(&At[cur][(mq + mi * 16 + c0) * 64 + px]);
#pragma unroll
            for (int ni = 0; ni < 4; ni++)
                bf_[ni] = *(const bf16x8*)(&Bt[cur][(nq + ni * 16 + c0) * 64 + px]);
#pragma unroll
            for (int mi = 0; mi < 4; mi++)
#pragma unroll
                for (int ni = 0; ni < 4; ni++)
                    acc[mi][ni] = MFMA16(af[mi], bf_[ni], acc[mi][ni], 0, 0, 0);
        }
        __syncthreads();
    }

    // ---- epilogue ----
#pragma unroll
    for (int ni = 0; ni < 4; ni++) {
        const int nloc = (nb & 1) * 128 + nq + ni * 16 + c0;
        const int h = nloc >> 5, c = nloc & 31;
        const float bg_ = (t == 3) ? bg[nloc] : 0.0f;
#pragma unroll
        for (int mi = 0; mi < 4; mi++) {
            const int mbase = m0 + mq + mi * 16 + g * 4;
            const int b2 = mbase >> 8;
            if (t == 2) {
                bf16x4 pk;
#pragma unroll
                for (int reg = 0; reg < 4; reg++) pk[reg] = (__bf16)acc[mi][ni][reg];
                *(bf16x4*)(&wsvT[((size_t)(b2 * NH + h) * CC + c) * LQK + (mbase & 255)]) = pk;
            } else if (t == 3) {
                bf16x4 pk;
#pragma unroll
                for (int reg = 0; reg < 4; reg++)
                    pk[reg] = (__bf16)(1.0f / (1.0f + __expf(-(acc[mi][ni][reg] + bg_))));
                *(bf16x4*)(&wsgT[((size_t)(b2 * NH + h) * CC + c) * LQK + (mbase & 255)]) = pk;
            } else {
#pragma unroll
                for (int reg = 0; reg < 4; reg++) {
                    const int l = (mbase + reg) & 255;
                    float v = acc[mi][ni][reg];
                    size_t idx = ((size_t)(b2 * NH + h) * LQK + l) * CC + c;
                    if (t == 0) wsq[idx] = (__bf16)(v * 0.17677669529663689f);
                    else        wsk[idx] = (__bf16)v;
                }
            }
        }
    }
}

// ---------------- Kernel 2: attention (q-phased; reg-dbuf operands) -------
// grid 4096; XCD head-grouping. 4 phases of 16 q-rows x all 256 k.
// Per phase: stage(p+1) + reg-load(p+1) issued first; compute phase p uses
// only LDS + resident regs (zero VMEM wait); barrier drains p+1's loads
// under compute. Kills the per-phase exposed q/nbb/gate latency.
__global__ __launch_bounds__(256, 3) void k_attn(
    const __bf16* __restrict__ wsq, const __bf16* __restrict__ wsk,
    const __bf16* __restrict__ wsvT, const __bf16* __restrict__ wsgT,
    const float* __restrict__ bias, const float* __restrict__ nbb,
    __bf16* __restrict__ wswa)
{
    __shared__ float  Bl[2][16][256];   // 32 KB: 16 full bias rows, dbuf
    __shared__ __bf16 P[4][16][TP];     // 9 KB wave-private P (k-local 64)
    __shared__ float  lsum[4][16];      // row-sum partials
    __shared__ float  op[4][16][33];    // 8.25 KB O k-partials (padded)

    const int tid = threadIdx.x;
    const int u0 = blockIdx.x;
    const int xcd = u0 & 7, slot = u0 >> 3;
    const int head = xcd + 8 * (slot >> 2);
    const int qt = slot & 3;
    const int b2 = head >> 3, h = head & 7;

    const int lane = tid & 63, w = tid >> 6;
    const int g = lane >> 4, kg = g * 8, c0 = lane & 15;

    const __bf16* qp = wsq + (size_t)(b2 * NH + h) * LQK * CC;
    const __bf16* kp = wsk + (size_t)(b2 * NH + h) * LQK * CC;
    const __bf16* vT = wsvT + (size_t)(b2 * NH + h) * CC * LQK;
    const __bf16* gT = wsgT + (size_t)(b2 * NH + h) * CC * LQK;
    const float* npb = nbb + (size_t)h * LQK * LQK;
    const float* bblk = bias + ((size_t)(b2 * NH + h) * LQK + qt * 64) * LQK;

    auto stage = [&](int buf, int p) {
#pragma unroll
        for (int i = 0; i < 4; i++) {
            const int row = w * 4 + i;                     // 0..15 in phase
            gload_lds16(bblk + (size_t)(p * 16 + row) * LQK + ((lane ^ row) * 4),
                        &Bl[buf][row][0]);
        }
    };

    // K/V fragments phase-invariant (wave k-slice fixed): load once.
    bf16x8 kf[4], vf[4];
#pragma unroll
    for (int j = 0; j < 4; j++)
        kf[j] = *(const bf16x8*)(kp + (size_t)(w * 64 + j * 16 + c0) * CC + kg);
#pragma unroll
    for (int kt2 = 0; kt2 < 2; kt2++)
#pragma unroll
        for (int vn = 0; vn < 2; vn++)
            vf[kt2 * 2 + vn] = *(const bf16x8*)(
                vT + (size_t)(vn * 16 + c0) * LQK + w * 64 + kt2 * 32 + kg);

    // reduce-step indexing (constant across phases)
    const int ridx = tid * 2;
    const int rqr = ridx >> 5;            // 0..15
    const int rcb = ridx & 31;            // even col base

    // per-phase register operands, double-buffered
    bf16x8 qfb[2];
    f32x4 nb4b[2][4];
    float gab[2], gbb[2];
    auto loadregs = [&](int buf, int p) {
        const int qglob = qt * 64 + p * 16 + c0;
        qfb[buf] = *(const bf16x8*)(qp + (size_t)qglob * CC + kg);
#pragma unroll
        for (int j = 0; j < 4; j++)
            nb4b[buf][j] = *(const f32x4*)(npb + (size_t)qglob * LQK + w * 64 + j * 16 + g * 4);
        const int qg = qt * 64 + p * 16 + rqr;
        gab[buf] = (float)gT[(size_t)rcb * LQK + qg];
        gbb[buf] = (float)gT[(size_t)(rcb + 1) * LQK + qg];
    };

    stage(0, 0);
    loadregs(0, 0);
    __syncthreads();                      // drains stage0 + regs0

#pragma unroll
    for (int p = 0; p < 4; p++) {
        const int cur = p & 1;

        // issue NEXT phase's stage + register operands (hidden under compute)
        if (p < 3) {
            stage(cur ^ 1, p + 1);
            loadregs(cur ^ 1, p + 1);
        }
        __builtin_amdgcn_sched_barrier(0);

        // ---- compute phase p: LDS + resident regs only ----
        float csum = 0.0f;
#pragma unroll
        for (int j = 0; j < 4; j++) {
            f32x4 b4 = *(const f32x4*)(&Bl[cur][c0][(w * 16 + ((j * 4 + g) ^ c0)) * 4]);
            f32x4 cc;
#pragma unroll
            for (int r2 = 0; r2 < 4; r2++) cc[r2] = b4[r2] + nb4b[cur][j][r2];
            f32x4 s = MFMA16(kf[j], qfb[cur], cc, 0, 0, 0);
            bf16x4 pk;
#pragma unroll
            for (int r2 = 0; r2 < 4; r2++) {
                float e = __expf(s[r2]);      // no max-sub: |s| bounded ~20
                csum += e;
                pk[r2] = (__bf16)e;
            }
            *(bf16x4*)(&P[w][c0][j * 16 + g * 4]) = pk;
        }
        csum += __shfl_xor(csum, 16);
        csum += __shfl_xor(csum, 32);
        if (lane < 16) lsum[w][lane] = csum;

        f32x4 o2[2] = {};
#pragma unroll
        for (int kt2 = 0; kt2 < 2; kt2++) {
            bf16x8 pa = *(const bf16x8*)(&P[w][c0][kt2 * 32 + kg]);
#pragma unroll
            for (int vn = 0; vn < 2; vn++)
                o2[vn] = MFMA16(pa, vf[kt2 * 2 + vn], o2[vn], 0, 0, 0);
        }
#pragma unroll
        for (int vn = 0; vn < 2; vn++)
#pragma unroll
            for (int r2 = 0; r2 < 4; r2++)
                op[w][g * 4 + r2][vn * 16 + c0] = o2[vn][r2];

        __syncthreads();                  // op/lsum ready; drains p+1 loads

        // ---- cross-wave reduce + gate (from regs) + store ----
        {
            const int qg = qt * 64 + p * 16 + rqr;
            const float li = 1.0f / (lsum[0][rqr] + lsum[1][rqr] + lsum[2][rqr] + lsum[3][rqr]);
            float v0 = op[0][rqr][rcb] + op[1][rqr][rcb] + op[2][rqr][rcb] + op[3][rqr][rcb];
            float v1 = op[0][rqr][rcb + 1] + op[1][rqr][rcb + 1] + op[2][rqr][rcb + 1] + op[3][rqr][rcb + 1];
            v0 *= li * gab[cur];
            v1 *= li * gbb[cur];
            __bf16* dst = &wswa[((size_t)(b2 * LQK + qg)) * (NH * CC) + h * CC + rcb];
            dst[0] = (__bf16)v0;
            dst[1] = (__bf16)v1;
        }
        __syncthreads();                  // op/lsum WAR safety
    }
}

// ---------------- Kernel 3: output projection (gload_lds GEMM) ------------
__global__ __launch_bounds__(256, 2) void k_out(
    const __bf16* __restrict__ wa, const __bf16* __restrict__ wBF,
    const float* __restrict__ bo, float* __restrict__ out)
{
    __shared__ __bf16 At[2][128 * 64];
    __shared__ __bf16 Bt[2][128 * 64];

    const int mb = blockIdx.x, nb = blockIdx.y;
    const __bf16* W = wBF + ((size_t)4 << 16) + (size_t)(nb * 128) * 256;

    const int tid = threadIdx.x;
    const int lane = tid & 63, w = tid >> 6;
    const int g = lane >> 4, c0 = lane & 15;
    const int mq = (w >> 1) * 64, nq = (w & 1) * 64;
    const int m0 = mb * 128;
    const int lrow = lane >> 3, lu = lane & 7;

    auto stage = [&](int buf, int kt) {
#pragma unroll
        for (int i = 0; i < 4; i++) {
            const int rr = i * 32 + w * 8 + lrow;
            const int su = lu ^ (rr & 7);
            gload_lds16(wa + (size_t)(m0 + rr) * 256 + kt * 64 + su * 8,
                        &At[buf][(i * 4 + w) * 512]);
        }
#pragma unroll
        for (int i = 0; i < 4; i++) {
            const int rr = i * 32 + w * 8 + lrow;
            const int su = lu ^ (rr & 7);
            gload_lds16(W + (size_t)rr * 256 + kt * 64 + su * 8,
                        &Bt[buf][(i * 4 + w) * 512]);
        }
    };

    f32x4 acc[4][4] = {};
    stage(0, 0);
    __syncthreads();

#pragma unroll
    for (int kt = 0; kt < 4; kt++) {
        const int cur = kt & 1;
        if (kt < 3) stage(cur ^ 1, kt + 1);
#pragma unroll
        for (int ks = 0; ks < 2; ks++) {
            const int px = ((ks * 4 + g) ^ (c0 & 7)) * 8;
            bf16x8 af[4], bf_[4];
#pragma unroll
            for (int mi = 0; mi < 4; mi++)
                af[mi] = *(const bf16x8*)(&At[cur][(mq + mi * 16 + c0) * 64 + px]);
#pragma unroll
            for (int ni = 0; ni < 4; ni++)
                bf_[ni] = *(const bf16x8*)(&Bt[cur][(nq + ni * 16 + c0) * 64 + px]);
#pragma unroll
            for (int mi = 0; mi < 4; mi++)
#pragma unroll
                for (int ni = 0; ni < 4; ni++)
                    acc[mi][ni] = MFMA16(af[mi], bf_[ni], acc[mi][ni], 0, 0, 0);
        }
        __syncthreads();
    }

#pragma unroll
    for (int ni = 0; ni < 4; ni++) {
        const int n = nb * 128 + nq + ni * 16 + c0;
        const float bo_ = bo[n];
#pragma unroll
        for (int mi = 0; mi < 4; mi++) {
            const int mbase = m0 + mq + mi * 16 + g * 4;
#pragma unroll
            for (int reg = 0; reg < 4; reg++)
                out[(size_t)(mbase + reg) * 256 + n] = acc[mi][ni][reg] + bo_;
        }
    }
}

// ---------------- launcher ------------------------------------------------
extern "C" void kernel_launch(void* const* d_in, const int* in_sizes, int n_in,
                              void* d_out, int out_size, void* d_ws, size_t ws_size,
                              hipStream_t stream) {
    const float* qd  = (const float*)d_in[0];
    const float* kvd = (const float*)d_in[1];
    const float* bias = (const float*)d_in[2];
    const float* nbb = (const float*)d_in[3];
    const float* Wq = (const float*)d_in[4];
    const float* Wk = (const float*)d_in[5];
    const float* Wv = (const float*)d_in[6];
    const float* Wg = (const float*)d_in[7];
    const float* bg = (const float*)d_in[8];
    const float* Wo = (const float*)d_in[9];
    const float* bo = (const float*)d_in[10];
    float* out = (float*)d_out;

    __bf16* ws = (__bf16*)d_ws;
    __bf16* wsq  = ws;
    __bf16* wsk  = wsq + NTOK;
    __bf16* wsvT = wsk + NTOK;
    __bf16* wsgT = wsvT + NTOK;
    __bf16* wBF  = wsgT + NTOK;            // 5 * 65536 bf16 weights
    __bf16* qbf  = wBF + 5 * 65536;        // activations bf16 (dead after k_proj)
    __bf16* kvbf = qbf + NTOK;
    __bf16* wswa = qbf;                    // alias: written by k_attn after k_proj

    k_cvt<<<dim3(8512), 256, 0, stream>>>(qd, kvd, Wq, Wk, Wv, Wg, Wo,
                                          qbf, kvbf, wBF);
    k_proj<<<dim3(256, 8), 256, 0, stream>>>(qbf, kvbf, wBF, bg,
                                             wsq, wsk, wsvT, wsgT);
    k_attn<<<dim3(4096), 256, 0, stream>>>(wsq, wsk, wsvT, wsgT, bias, nbb, wswa);
    k_out<<<dim3(256, 2), 256, 0, stream>>>(wswa, wBF, bo, out);
}

// Round 19
// 155.682 us; speedup vs baseline: 1.1763x; 1.0207x over previous
//
#include <hip/hip_runtime.h>
#include <hip/hip_bf16.h>

// dims
#define NB2 128
#define LQK 256
#define DIM 256
#define NH 8
#define CC 32

typedef __bf16 bf16x8 __attribute__((ext_vector_type(8)));
typedef __bf16 bf16x4 __attribute__((ext_vector_type(4)));
typedef __bf16 bf16x2 __attribute__((ext_vector_type(2)));
typedef float f32x4 __attribute__((ext_vector_type(4)));

#define MFMA16 __builtin_amdgcn_mfma_f32_16x16x32_bf16

// LDS tile row stride (bf16) for k_attn P: must stay ≡0 mod 8 elems (b128)
#define TP 72

#define NTOK ((size_t)NB2 * LQK * NH * CC)   // 8,388,608

// async global->LDS, 16B per lane; LDS dest is wave-uniform base + lane*16
static __device__ __forceinline__ void gload_lds16(const void* g, void* l) {
    __builtin_amdgcn_global_load_lds(
        (const __attribute__((address_space(1))) unsigned int*)g,
        (__attribute__((address_space(3))) unsigned int*)l,
        16, 0, 0);
}

// ---------------- Kernel 0: fp32 -> bf16 (activations + weights) ----------
__global__ __launch_bounds__(256) void k_cvt(
    const float* __restrict__ qd, const float* __restrict__ kvd,
    const float* __restrict__ Wq, const float* __restrict__ Wk,
    const float* __restrict__ Wv, const float* __restrict__ Wg,
    const float* __restrict__ Wo,
    __bf16* __restrict__ qbf, __bf16* __restrict__ kvbf,
    __bf16* __restrict__ wBF)
{
    const int b = blockIdx.x;
    if (b < 8192) {
        size_t i = ((size_t)b * 256 + threadIdx.x) * 8;
        const float* src;
        __bf16* dst;
        if (i < NTOK) { src = qd + i; dst = qbf + i; }
        else          { src = kvd + (i - NTOK); dst = kvbf + (i - NTOK); }
        f32x4 a = *(const f32x4*)src;
        f32x4 c = *(const f32x4*)(src + 4);
        bf16x8 r;
        r[0] = (__bf16)a[0]; r[1] = (__bf16)a[1]; r[2] = (__bf16)a[2]; r[3] = (__bf16)a[3];
        r[4] = (__bf16)c[0]; r[5] = (__bf16)c[1]; r[6] = (__bf16)c[2]; r[7] = (__bf16)c[3];
        *(bf16x8*)dst = r;
    } else {
        int i = ((b - 8192) * 256 + threadIdx.x) * 4;
        int mat = i >> 16;
        int off = i & 65535;
        const float* src = (mat == 0) ? Wq : (mat == 1) ? Wk : (mat == 2) ? Wv
                          : (mat == 3) ? Wg : Wo;
        f32x4 v = *(const f32x4*)(src + off);
        __bf16* d = wBF + ((size_t)mat << 16) + off;
        d[0] = (__bf16)v[0]; d[1] = (__bf16)v[1]; d[2] = (__bf16)v[2]; d[3] = (__bf16)v[3];
    }
}

// ---------------- Kernel 1: QKVG projection (gload_lds GEMM) --------------
__global__ __launch_bounds__(256, 2) void k_proj(
    const __bf16* __restrict__ qbf, const __bf16* __restrict__ kvbf,
    const __bf16* __restrict__ wBF, const float* __restrict__ bg,
    __bf16* __restrict__ wsq, __bf16* __restrict__ wsk,
    __bf16* __restrict__ wsvT, __bf16* __restrict__ wsg)
{
    __shared__ __bf16 At[2][128 * 64];
    __shared__ __bf16 Bt[2][128 * 64];

    const int mb = blockIdx.x, nb = blockIdx.y;
    const int t = nb >> 1;                       // 0=q 1=k 2=v 3=g
    const __bf16* X = (t == 0 || t == 3) ? qbf : kvbf;
    const __bf16* W = wBF + ((size_t)t << 16) + (size_t)((nb & 1) * 128) * 256;

    const int tid = threadIdx.x;
    const int lane = tid & 63, w = tid >> 6;
    const int g = lane >> 4, c0 = lane & 15;
    const int mq = (w >> 1) * 64, nq = (w & 1) * 64;
    const int m0 = mb * 128;
    const int lrow = lane >> 3, lu = lane & 7;   // staging row-sub / unit

    auto stage = [&](int buf, int kt) {
#pragma unroll
        for (int i = 0; i < 4; i++) {
            const int rr = i * 32 + w * 8 + lrow;          // 0..127
            const int su = lu ^ (rr & 7);                  // src-unit swizzle
            gload_lds16(X + (size_t)(m0 + rr) * 256 + kt * 64 + su * 8,
                        &At[buf][(i * 4 + w) * 512]);
        }
#pragma unroll
        for (int i = 0; i < 4; i++) {
            const int rr = i * 32 + w * 8 + lrow;
            const int su = lu ^ (rr & 7);
            gload_lds16(W + (size_t)rr * 256 + kt * 64 + su * 8,
                        &Bt[buf][(i * 4 + w) * 512]);
        }
    };

    f32x4 acc[4][4] = {};
    stage(0, 0);
    __syncthreads();

#pragma unroll
    for (int kt = 0; kt < 4; kt++) {
        const int cur = kt & 1;
        if (kt < 3) stage(cur ^ 1, kt + 1);      // async; drains at barrier
#pragma unroll
        for (int ks = 0; ks < 2; ks++) {
            const int px = ((ks * 4 + g) ^ (c0 & 7)) * 8;  // phys unit offset
            bf16x8 af[4], bf_[4];
#pragma unroll
            for (int mi = 0; mi < 4; mi++)
                af[mi] = *(const bf16x8*)(&At[cur][(mq + mi * 16 + c0) * 64 + px]);
#pragma unroll
            for (int ni = 0; ni < 4; ni++)
                bf_[ni] = *(const bf16x8*)(&Bt[cur][(nq + ni * 16 + c0) * 64 + px]);
#pragma unroll
            for (int mi = 0; mi < 4; mi++)
#pragma unroll
                for (int ni = 0; ni < 4; ni++)
                    acc[mi][ni] = MFMA16(af[mi], bf_[ni], acc[mi][ni], 0, 0, 0);
        }
        __syncthreads();
    }

    // ---- epilogue ----
#pragma unroll
    for (int ni = 0; ni < 4; ni++) {
        const int nloc = (nb & 1) * 128 + nq + ni * 16 + c0;
        const int h = nloc >> 5, c = nloc & 31;
        const float bg_ = (t == 3) ? bg[nloc] : 0.0f;
#pragma unroll
        for (int mi = 0; mi < 4; mi++) {
            const int mbase = m0 + mq + mi * 16 + g * 4;
            const int b2 = mbase >> 8;
            if (t == 2) {
                bf16x4 pk;
#pragma unroll
                for (int reg = 0; reg < 4; reg++) pk[reg] = (__bf16)acc[mi][ni][reg];
                *(bf16x4*)(&wsvT[((size_t)(b2 * NH + h) * CC + c) * LQK + (mbase & 255)]) = pk;
            } else {
#pragma unroll
                for (int reg = 0; reg < 4; reg++) {
                    const int l = (mbase + reg) & 255;
                    float v = acc[mi][ni][reg];
                    size_t idx = ((size_t)(b2 * NH + h) * LQK + l) * CC + c;
                    if (t == 0)      wsq[idx] = (__bf16)(v * 0.17677669529663689f);
                    else if (t == 1) wsk[idx] = (__bf16)v;
                    else             wsg[idx] = (__bf16)(1.0f / (1.0f + __expf(-(v + bg_))));
                }
            }
        }
    }
}

// ---------------- Kernel 2: attention (q-phased; 1 barrier/phase) ---------
// grid 4096; XCD head-grouping. 4 phases of 16 q-rows x all 256 k.
// Phase p (buffer cur=p&1): [reduce(p-1) from buffers ~cur]
// [stage(p+1)+loadregs(p+1) into ~cur] [compute(buffer cur)] [barrier].
// NOTE: compute() takes the BUFFER index (p&1), not the phase number
// (round-18 bug: compute(2)/compute(3) indexed Bl[2]/Bl[3] OOB).
__global__ __launch_bounds__(256, 3) void k_attn(
    const __bf16* __restrict__ wsq, const __bf16* __restrict__ wsk,
    const __bf16* __restrict__ wsvT, const __bf16* __restrict__ wsg,
    const float* __restrict__ bias, const float* __restrict__ nbb,
    __bf16* __restrict__ wswa)
{
    __shared__ float  Bl[2][16][256];     // 32 KB: 16 full bias rows, dbuf
    __shared__ __bf16 P[4][16][TP];       // 9 KB wave-private P
    __shared__ float  lsum[2][4][16];     // row-sum partials, dbuf
    __shared__ __bf16 op[2][4][16][40];   // 10 KB O k-partials bf16, dbuf

    const int tid = threadIdx.x;
    const int u0 = blockIdx.x;
    const int xcd = u0 & 7, slot = u0 >> 3;
    const int head = xcd + 8 * (slot >> 2);
    const int qt = slot & 3;
    const int b2 = head >> 3, h = head & 7;

    const int lane = tid & 63, w = tid >> 6;
    const int g = lane >> 4, kg = g * 8, c0 = lane & 15;

    const __bf16* qp = wsq + (size_t)(b2 * NH + h) * LQK * CC;
    const __bf16* kp = wsk + (size_t)(b2 * NH + h) * LQK * CC;
    const __bf16* vT = wsvT + (size_t)(b2 * NH + h) * CC * LQK;
    const __bf16* gR = wsg + (size_t)(b2 * NH + h) * LQK * CC;   // row-major
    const float* npb = nbb + (size_t)h * LQK * LQK;
    const float* bblk = bias + ((size_t)(b2 * NH + h) * LQK + qt * 64) * LQK;

    auto stage = [&](int buf, int p) {
#pragma unroll
        for (int i = 0; i < 4; i++) {
            const int row = w * 4 + i;                     // 0..15 in phase
            gload_lds16(bblk + (size_t)(p * 16 + row) * LQK + ((lane ^ row) * 4),
                        &Bl[buf][row][0]);
        }
    };

    // K/V fragments phase-invariant (wave k-slice fixed): load once.
    bf16x8 kf[4], vf[4];
#pragma unroll
    for (int j = 0; j < 4; j++)
        kf[j] = *(const bf16x8*)(kp + (size_t)(w * 64 + j * 16 + c0) * CC + kg);
#pragma unroll
    for (int kt2 = 0; kt2 < 2; kt2++)
#pragma unroll
        for (int vn = 0; vn < 2; vn++)
            vf[kt2 * 2 + vn] = *(const bf16x8*)(
                vT + (size_t)(vn * 16 + c0) * LQK + w * 64 + kt2 * 32 + kg);

    // reduce-step indexing (constant across phases)
    const int ridx = tid * 2;
    const int rqr = ridx >> 5;            // 0..15
    const int rcb = ridx & 31;            // even col base

    // per-phase register operands, double-buffered
    bf16x8 qfb[2];
    f32x4 nb4b[2][4];
    bf16x2 g2b[2];
    auto loadregs = [&](int buf, int p) {
        const int qglob = qt * 64 + p * 16 + c0;
        qfb[buf] = *(const bf16x8*)(qp + (size_t)qglob * CC + kg);
#pragma unroll
        for (int j = 0; j < 4; j++)
            nb4b[buf][j] = *(const f32x4*)(npb + (size_t)qglob * LQK + w * 64 + j * 16 + g * 4);
        const int qg = qt * 64 + p * 16 + rqr;
        g2b[buf] = *(const bf16x2*)(&gR[(size_t)qg * CC + rcb]);   // coalesced
    };

    auto compute = [&](int cur) {          // cur = BUFFER index = p&1
        float csum = 0.0f;
#pragma unroll
        for (int j = 0; j < 4; j++) {
            f32x4 b4 = *(const f32x4*)(&Bl[cur][c0][(w * 16 + ((j * 4 + g) ^ c0)) * 4]);
            f32x4 cc;
#pragma unroll
            for (int r2 = 0; r2 < 4; r2++) cc[r2] = b4[r2] + nb4b[cur][j][r2];
            f32x4 s = MFMA16(kf[j], qfb[cur], cc, 0, 0, 0);
            bf16x4 pk;
#pragma unroll
            for (int r2 = 0; r2 < 4; r2++) {
                float e = __expf(s[r2]);      // no max-sub: |s| bounded ~20
                csum += e;
                pk[r2] = (__bf16)e;
            }
            *(bf16x4*)(&P[w][c0][j * 16 + g * 4]) = pk;
        }
        csum += __shfl_xor(csum, 16);
        csum += __shfl_xor(csum, 32);
        if (lane < 16) lsum[cur][w][lane] = csum;

        f32x4 o2[2] = {};
#pragma unroll
        for (int kt2 = 0; kt2 < 2; kt2++) {
            bf16x8 pa = *(const bf16x8*)(&P[w][c0][kt2 * 32 + kg]);
#pragma unroll
            for (int vn = 0; vn < 2; vn++)
                o2[vn] = MFMA16(pa, vf[kt2 * 2 + vn], o2[vn], 0, 0, 0);
        }
#pragma unroll
        for (int vn = 0; vn < 2; vn++)
#pragma unroll
            for (int r2 = 0; r2 < 4; r2++)
                op[cur][w][g * 4 + r2][vn * 16 + c0] = (__bf16)o2[vn][r2];
    };

    auto reduce_store = [&](int p, int pb) {
        const int qg = qt * 64 + p * 16 + rqr;
        const float li = 1.0f /
            (lsum[pb][0][rqr] + lsum[pb][1][rqr] + lsum[pb][2][rqr] + lsum[pb][3][rqr]);
        float v0 = (float)op[pb][0][rqr][rcb]     + (float)op[pb][1][rqr][rcb]
                 + (float)op[pb][2][rqr][rcb]     + (float)op[pb][3][rqr][rcb];
        float v1 = (float)op[pb][0][rqr][rcb + 1] + (float)op[pb][1][rqr][rcb + 1]
                 + (float)op[pb][2][rqr][rcb + 1] + (float)op[pb][3][rqr][rcb + 1];
        v0 *= li * (float)g2b[pb][0];
        v1 *= li * (float)g2b[pb][1];
        __bf16* dst = &wswa[((size_t)(b2 * LQK + qg)) * (NH * CC) + h * CC + rcb];
        dst[0] = (__bf16)v0;
        dst[1] = (__bf16)v1;
    };

    stage(0, 0);
    loadregs(0, 0);
    __syncthreads();                      // drains stage0 + regs0

    // p=0 (buffer 0)
    stage(1, 1); loadregs(1, 1);
    __builtin_amdgcn_sched_barrier(0);
    compute(0);
    __syncthreads();
    // p=1 (buffer 1)
    reduce_store(0, 0);
    stage(0, 2); loadregs(0, 2);
    __builtin_amdgcn_sched_barrier(0);
    compute(1);
    __syncthreads();
    // p=2 (buffer 0)
    reduce_store(1, 1);
    stage(1, 3); loadregs(1, 3);
    __builtin_amdgcn_sched_barrier(0);
    compute(0);
    __syncthreads();
    // p=3 (buffer 1)
    reduce_store(2, 0);
    compute(1);
    __syncthreads();
    reduce_store(3, 1);
}

// ---------------- Kernel 3: output projection (gload_lds GEMM) ------------
__global__ __launch_bounds__(256, 2) void k_out(
    const __bf16* __restrict__ wa, const __bf16* __restrict__ wBF,
    const float* __restrict__ bo, float* __restrict__ out)
{
    __shared__ __bf16 At[2][128 * 64];
    __shared__ __bf16 Bt[2][128 * 64];

    const int mb = blockIdx.x, nb = blockIdx.y;
    const __bf16* W = wBF + ((size_t)4 << 16) + (size_t)(nb * 128) * 256;

    const int tid = threadIdx.x;
    const int lane = tid & 63, w = tid >> 6;
    const int g = lane >> 4, c0 = lane & 15;
    const int mq = (w >> 1) * 64, nq = (w & 1) * 64;
    const int m0 = mb * 128;
    const int lrow = lane >> 3, lu = lane & 7;

    auto stage = [&](int buf, int kt) {
#pragma unroll
        for (int i = 0; i < 4; i++) {
            const int rr = i * 32 + w * 8 + lrow;
            const int su = lu ^ (rr & 7);
            gload_lds16(wa + (size_t)(m0 + rr) * 256 + kt * 64 + su * 8,
                        &At[buf][(i * 4 + w) * 512]);
        }
#pragma unroll
        for (int i = 0; i < 4; i++) {
            const int rr = i * 32 + w * 8 + lrow;
            const int su = lu ^ (rr & 7);
            gload_lds16(W + (size_t)rr * 256 + kt * 64 + su * 8,
                        &Bt[buf][(i * 4 + w) * 512]);
        }
    };

    f32x4 acc[4][4] = {};
    stage(0, 0);
    __syncthreads();

#pragma unroll
    for (int kt = 0; kt < 4; kt++) {
        const int cur = kt & 1;
        if (kt < 3) stage(cur ^ 1, kt + 1);
#pragma unroll
        for (int ks = 0; ks < 2; ks++) {
            const int px = ((ks * 4 + g) ^ (c0 & 7)) * 8;
            bf16x8 af[4], bf_[4];
#pragma unroll
            for (int mi = 0; mi < 4; mi++)
                af[mi] = *(const bf16x8*)(&At[cur][(mq + mi * 16 + c0) * 64 + px]);
#pragma unroll
            for (int ni = 0; ni < 4; ni++)
                bf_[ni] = *(const bf16x8*)(&Bt[cur][(nq + ni * 16 + c0) * 64 + px]);
#pragma unroll
            for (int mi = 0; mi < 4; mi++)
#pragma unroll
                for (int ni = 0; ni < 4; ni++)
                    acc[mi][ni] = MFMA16(af[mi], bf_[ni], acc[mi][ni], 0, 0, 0);
        }
        __syncthreads();
    }

#pragma unroll
    for (int ni = 0; ni < 4; ni++) {
        const int n = nb * 128 + nq + ni * 16 + c0;
        const float bo_ = bo[n];
#pragma unroll
        for (int mi = 0; mi < 4; mi++) {
            const int mbase = m0 + mq + mi * 16 + g * 4;
#pragma unroll
            for (int reg = 0; reg < 4; reg++)
                out[(size_t)(mbase + reg) * 256 + n] = acc[mi][ni][reg] + bo_;
        }
    }
}

// ---------------- launcher ------------------------------------------------
extern "C" void kernel_launch(void* const* d_in, const int* in_sizes, int n_in,
                              void* d_out, int out_size, void* d_ws, size_t ws_size,
                              hipStream_t stream) {
    const float* qd  = (const float*)d_in[0];
    const float* kvd = (const float*)d_in[1];
    const float* bias = (const float*)d_in[2];
    const float* nbb = (const float*)d_in[3];
    const float* Wq = (const float*)d_in[4];
    const float* Wk = (const float*)d_in[5];
    const float* Wv = (const float*)d_in[6];
    const float* Wg = (const float*)d_in[7];
    const float* bg = (const float*)d_in[8];
    const float* Wo = (const float*)d_in[9];
    const float* bo = (const float*)d_in[10];
    float* out = (float*)d_out;

    __bf16* ws = (__bf16*)d_ws;
    __bf16* wsq  = ws;
    __bf16* wsk  = wsq + NTOK;
    __bf16* wsvT = wsk + NTOK;
    __bf16* wsg  = wsvT + NTOK;
    __bf16* wBF  = wsg + NTOK;             // 5 * 65536 bf16 weights
    __bf16* qbf  = wBF + 5 * 65536;        // activations bf16 (dead after k_proj)
    __bf16* kvbf = qbf + NTOK;
    __bf16* wswa = qbf;                    // alias: written by k_attn after k_proj

    k_cvt<<<dim3(8512), 256, 0, stream>>>(qd, kvd, Wq, Wk, Wv, Wg, Wo,
                                          qbf, kvbf, wBF);
    k_proj<<<dim3(256, 8), 256, 0, stream>>>(qbf, kvbf, wBF, bg,
                                             wsq, wsk, wsvT, wsg);
    k_attn<<<dim3(4096), 256, 0, stream>>>(wsq, wsk, wsvT, wsg, bias, nbb, wswa);
    k_out<<<dim3(256, 2), 256, 0, stream>>>(wswa, wBF, bo, out);
}